// Round 1
// baseline (1657.179 us; speedup 1.0000x reference)
//
#include <hip/hip_runtime.h>

#define BB 4
#define CC 128
#define HH 180
#define WWW 180
#define HWHW (HH*WWW)       // 32400
#define CCAMD 256
#define NHEADS 4
#define DHD 32
#define HDD 128
#define NT 20000
#define GAMMA_C 0.08f
#define EPS_C 1e-6f
#define SCALE_C 0.17677669529663687f  // 1/sqrt(32)

static __device__ __forceinline__ float warpMax(float v) {
#pragma unroll
  for (int o = 32; o >= 1; o >>= 1) v = fmaxf(v, __shfl_xor(v, o));
  return v;
}
static __device__ __forceinline__ float warpSum(float v) {
#pragma unroll
  for (int o = 32; o >= 1; o >>= 1) v += __shfl_xor(v, o);
  return v;
}

// ---------------------------------------------------------------------------
// K1: per-token projections. blockIdx.z: 0..3 -> v output-channel group,
//     4..7 -> logits for head (z-4) (computes q_h and k_h fused, stores logit).
// One token per lane. Weight addresses are wave-uniform -> scalar loads.
// ---------------------------------------------------------------------------
__global__ __launch_bounds__(256) void k_proj(
    const float* __restrict__ lidar,    // [B][C][HW]
    const float* __restrict__ tokens,   // [B][N][CCAM]
    const int* __restrict__ cidx,       // [B][N][2]
    const float* __restrict__ q_w,      // [HD][C]
    const float* __restrict__ q_bias,   // [HD]
    const float* __restrict__ k_w,      // [HD][CCAM]
    const float* __restrict__ v_w,      // [HD][CCAM]
    float* __restrict__ v_ws,           // [B][HD][N]
    float* __restrict__ logits)         // [B][HEADS][N]
{
  const int b = blockIdx.y;
  const int n = blockIdx.x * 256 + threadIdx.x;
  const bool act = (n < NT);
  const int nn = act ? n : (NT - 1);
  const float* tok = tokens + ((size_t)b * NT + nn) * CCAMD;
  const int z = blockIdx.z;

  if (z < 4) {
    // ---- v projection, channels [32z, 32z+32) ----
    const int og = z * 32;
    float acc[32];
#pragma unroll
    for (int o = 0; o < 32; ++o) acc[o] = 0.f;
    for (int cb = 0; cb < CCAMD; cb += 32) {
      float tc[32];
#pragma unroll
      for (int c = 0; c < 32; c += 4) {
        const float4 f = *reinterpret_cast<const float4*>(tok + cb + c);
        tc[c] = f.x; tc[c + 1] = f.y; tc[c + 2] = f.z; tc[c + 3] = f.w;
      }
#pragma unroll
      for (int o = 0; o < 32; ++o) {
        const float* wr = v_w + (size_t)(og + o) * CCAMD + cb;
#pragma unroll
        for (int c = 0; c < 32; ++c) acc[o] = fmaf(wr[c], tc[c], acc[o]);
      }
    }
    if (act) {
#pragma unroll
      for (int o = 0; o < 32; ++o)
        v_ws[((size_t)b * HDD + og + o) * NT + n] = acc[o];
    }
  } else {
    // ---- logits for head h: q_h = q_w_h @ x(pix) + bias, k_h = k_w_h @ tok ----
    const int h = z - 4;
    const int* ip = cidx + ((size_t)b * NT + nn) * 2;
    int ii = ip[0]; ii = ii < 0 ? 0 : (ii > HH - 1 ? HH - 1 : ii);
    int jj = ip[1]; jj = jj < 0 ? 0 : (jj > WWW - 1 ? WWW - 1 : jj);
    const int pix = ii * WWW + jj;

    float q[32];
#pragma unroll
    for (int d = 0; d < 32; ++d) q[d] = q_bias[h * 32 + d];
    for (int xb = 0; xb < CC; xb += 32) {
      float xc[32];
#pragma unroll
      for (int c = 0; c < 32; ++c)
        xc[c] = lidar[((size_t)b * CC + xb + c) * HWHW + pix];
#pragma unroll
      for (int d = 0; d < 32; ++d) {
        const float* wr = q_w + (size_t)(h * 32 + d) * CC + xb;
#pragma unroll
        for (int c = 0; c < 32; ++c) q[d] = fmaf(wr[c], xc[c], q[d]);
      }
    }

    float kk[32];
#pragma unroll
    for (int d = 0; d < 32; ++d) kk[d] = 0.f;
    for (int cb = 0; cb < CCAMD; cb += 32) {
      float tc[32];
#pragma unroll
      for (int c = 0; c < 32; c += 4) {
        const float4 f = *reinterpret_cast<const float4*>(tok + cb + c);
        tc[c] = f.x; tc[c + 1] = f.y; tc[c + 2] = f.z; tc[c + 3] = f.w;
      }
#pragma unroll
      for (int d = 0; d < 32; ++d) {
        const float* wr = k_w + (size_t)(h * 32 + d) * CCAMD + cb;
#pragma unroll
        for (int c = 0; c < 32; ++c) kk[d] = fmaf(wr[c], tc[c], kk[d]);
      }
    }

    float lg = 0.f;
#pragma unroll
    for (int d = 0; d < 32; ++d) lg = fmaf(q[d], kk[d], lg);
    if (act) logits[((size_t)b * NHEADS + h) * NT + n] = lg * SCALE_C;
  }
}

// ---------------------------------------------------------------------------
// K2: softmax over N per (b,h), in-place on logits, then *gate.
// ---------------------------------------------------------------------------
__global__ __launch_bounds__(256) void k_softmax(
    float* __restrict__ logits, const float* __restrict__ gate)
{
  const int bh = blockIdx.x;
  const int b = bh / NHEADS;
  float* L = logits + (size_t)bh * NT;
  const float* g = gate + (size_t)b * NT;
  __shared__ float sred[4];
  const int tid = threadIdx.x;

  float m = -INFINITY;
  for (int i = tid; i < NT; i += 256) m = fmaxf(m, L[i]);
  m = warpMax(m);
  if ((tid & 63) == 0) sred[tid >> 6] = m;
  __syncthreads();
  m = fmaxf(fmaxf(sred[0], sred[1]), fmaxf(sred[2], sred[3]));

  float s = 0.f;
  for (int i = tid; i < NT; i += 256) s += __expf(L[i] - m);
  s = warpSum(s);
  __syncthreads();
  if ((tid & 63) == 0) sred[tid >> 6] = s;
  __syncthreads();
  s = sred[0] + sred[1] + sred[2] + sred[3];
  const float inv = 1.0f / s;

  for (int i = tid; i < NT; i += 256) L[i] = __expf(L[i] - m) * inv * g[i];
}

// ---------------------------------------------------------------------------
// K3: out_tok = out_w @ (attn (.) v), scatter-add into delta (= d_out) + hits.
// blockIdx.z = output-channel group (32 channels each).
// ---------------------------------------------------------------------------
__global__ __launch_bounds__(256) void k_out(
    const float* __restrict__ v_ws,     // [B][HD][N]
    const float* __restrict__ attn,     // [B][HEADS][N]
    const int* __restrict__ cidx,
    const float* __restrict__ out_w,    // [C][HD]
    float* __restrict__ delta,          // [B][C][HW]
    float* __restrict__ hits)           // [B][HW]
{
  const int b = blockIdx.y;
  const int cg = blockIdx.z;
  const int n = blockIdx.x * 256 + threadIdx.x;
  if (n >= NT) return;

  const int* ip = cidx + ((size_t)b * NT + n) * 2;
  int ii = ip[0]; ii = ii < 0 ? 0 : (ii > HH - 1 ? HH - 1 : ii);
  int jj = ip[1]; jj = jj < 0 ? 0 : (jj > WWW - 1 ? WWW - 1 : jj);
  const int pix = ii * WWW + jj;

  float at[NHEADS];
#pragma unroll
  for (int h = 0; h < NHEADS; ++h)
    at[h] = attn[((size_t)b * NHEADS + h) * NT + n];

  float acc[32];
#pragma unroll
  for (int c = 0; c < 32; ++c) acc[c] = 0.f;

#pragma unroll
  for (int ob = 0; ob < HDD; ob += 32) {
    const float ah = at[ob >> 5];
    float vv[32];
#pragma unroll
    for (int o = 0; o < 32; ++o)
      vv[o] = v_ws[((size_t)b * HDD + ob + o) * NT + n] * ah;
#pragma unroll
    for (int c = 0; c < 32; ++c) {
      const float* wr = out_w + (size_t)(cg * 32 + c) * HDD + ob;
#pragma unroll
      for (int o = 0; o < 32; ++o) acc[c] = fmaf(wr[o], vv[o], acc[c]);
    }
  }

  float* dbase = delta + ((size_t)b * CC + cg * 32) * HWHW + pix;
#pragma unroll
  for (int c = 0; c < 32; ++c) atomicAdd(dbase + (size_t)c * HWHW, acc[c]);
  if (cg == 0) atomicAdd(hits + (size_t)b * HWHW + pix, 1.0f);
}

// ---------------------------------------------------------------------------
// K4a: cnt[b] = number of hit pixels
// ---------------------------------------------------------------------------
__global__ __launch_bounds__(256) void k_cnt(
    const float* __restrict__ hits, float* __restrict__ cnt)
{
  const int b = blockIdx.x;
  const int tid = threadIdx.x;
  float s = 0.f;
  for (int i = tid; i < HWHW; i += 256)
    s += (hits[(size_t)b * HWHW + i] > 0.f) ? 1.f : 0.f;
  s = warpSum(s);
  __shared__ float sred[4];
  if ((tid & 63) == 0) sred[tid >> 6] = s;
  __syncthreads();
  if (tid == 0) cnt[b] = sred[0] + sred[1] + sred[2] + sred[3];
}

// ---------------------------------------------------------------------------
// K4b: mean[b][c] = sum_hw delta / (cnt[b] + eps)   (delta==0 off-hits)
// ---------------------------------------------------------------------------
__global__ __launch_bounds__(256) void k_mean(
    const float* __restrict__ delta, const float* __restrict__ cnt,
    float* __restrict__ mean)
{
  const int b = blockIdx.y, c = blockIdx.x;
  const float* row = delta + ((size_t)b * CC + c) * HWHW;
  const int tid = threadIdx.x;
  float s = 0.f;
  for (int i = tid; i < HWHW; i += 256) s += row[i];
  s = warpSum(s);
  __shared__ float sred[4];
  if ((tid & 63) == 0) sred[tid >> 6] = s;
  __syncthreads();
  if (tid == 0)
    mean[b * CC + c] = (sred[0] + sred[1] + sred[2] + sred[3]) / (cnt[b] + EPS_C);
}

// ---------------------------------------------------------------------------
// K5: out = lidar + (delta - mean*mask) * alpha * gamma   (in-place on delta)
// ---------------------------------------------------------------------------
__global__ __launch_bounds__(256) void k_final(
    const float* __restrict__ lidar, const float* __restrict__ alpha,
    const float* __restrict__ hits, const float* __restrict__ mean,
    float* __restrict__ out)
{
  const size_t total4 = (size_t)BB * CC * HWHW / 4;
  for (size_t i4 = (size_t)blockIdx.x * blockDim.x + threadIdx.x; i4 < total4;
       i4 += (size_t)gridDim.x * blockDim.x) {
    const size_t i = i4 * 4;
    const int b = (int)(i / ((size_t)CC * HWHW));
    const int r = (int)(i - (size_t)b * CC * HWHW);
    const int c = r / HWHW;
    const int hw = r - c * HWHW;

    const float4 d = *reinterpret_cast<const float4*>(out + i);
    const float4 li = *reinterpret_cast<const float4*>(lidar + i);
    const float4 al = *reinterpret_cast<const float4*>(alpha + hw);
    const float4 ht = *reinterpret_cast<const float4*>(hits + (size_t)b * HWHW + hw);
    const float mn = mean[b * CC + c];

    float4 o;
    o.x = li.x + (d.x - (ht.x > 0.f ? mn : 0.f)) * al.x * GAMMA_C;
    o.y = li.y + (d.y - (ht.y > 0.f ? mn : 0.f)) * al.y * GAMMA_C;
    o.z = li.z + (d.z - (ht.z > 0.f ? mn : 0.f)) * al.z * GAMMA_C;
    o.w = li.w + (d.w - (ht.w > 0.f ? mn : 0.f)) * al.w * GAMMA_C;
    *reinterpret_cast<float4*>(out + i) = o;
  }
}

extern "C" void kernel_launch(void* const* d_in, const int* in_sizes, int n_in,
                              void* d_out, int out_size, void* d_ws, size_t ws_size,
                              hipStream_t stream)
{
  const float* lidar  = (const float*)d_in[0];
  const float* tokens = (const float*)d_in[1];
  const float* gate   = (const float*)d_in[2];
  const float* alpha  = (const float*)d_in[3];
  const float* q_w    = (const float*)d_in[4];
  const float* q_b    = (const float*)d_in[5];
  const float* k_w    = (const float*)d_in[6];
  const float* v_w    = (const float*)d_in[7];
  const float* out_w  = (const float*)d_in[8];
  const int*   cidx   = (const int*)d_in[9];
  float* out = (float*)d_out;

  float* ws = (float*)d_ws;
  float* v_ws   = ws;                                   // B*HD*N   = 10,240,000
  float* logits = v_ws + (size_t)BB * HDD * NT;         // B*H*N    = 320,000
  float* hits   = logits + (size_t)BB * NHEADS * NT;    // B*HW     = 129,600
  float* mean   = hits + (size_t)BB * HWHW;             // B*C      = 512
  float* cnt    = mean + BB * CC;                       // B        = 4

  hipMemsetAsync(d_out, 0, (size_t)out_size * sizeof(float), stream);
  hipMemsetAsync(hits, 0, (size_t)BB * HWHW * sizeof(float), stream);

  const int nb = (NT + 255) / 256;  // 79
  k_proj<<<dim3(nb, BB, 8), 256, 0, stream>>>(lidar, tokens, cidx, q_w, q_b,
                                              k_w, v_w, v_ws, logits);
  k_softmax<<<dim3(BB * NHEADS), 256, 0, stream>>>(logits, gate);
  k_out<<<dim3(nb, BB, 4), 256, 0, stream>>>(v_ws, logits, cidx, out_w, out, hits);
  k_cnt<<<dim3(BB), 256, 0, stream>>>(hits, cnt);
  k_mean<<<dim3(CC, BB), 256, 0, stream>>>(out, cnt, mean);
  k_final<<<dim3(4096), 256, 0, stream>>>(lidar, alpha, hits, mean, out);
}

// Round 2
// 467.111 us; speedup vs baseline: 3.5477x; 3.5477x over previous
//
#include <hip/hip_runtime.h>

#define BB 4
#define CC 128
#define HH 180
#define WWW 180
#define HWHW (HH*WWW)       // 32400
#define CCAMD 256
#define NHEADS 4
#define HDD 128
#define NT 20000
#define MTOT 80000          // B*N, = 625 * 128 exactly
#define GAMMA_C 0.08f
#define EPS_C 1e-6f
#define SCALE_C 0.17677669529663687f  // 1/sqrt(32)

typedef short bf16x8 __attribute__((ext_vector_type(8)));
typedef float f32x4 __attribute__((ext_vector_type(4)));

typedef __attribute__((address_space(1))) const unsigned int GU;
typedef __attribute__((address_space(3))) unsigned int LU;

static __device__ __forceinline__ void gll16(const void* g, void* l) {
  __builtin_amdgcn_global_load_lds((GU*)g, (LU*)l, 16, 0, 0);
}

static __device__ __forceinline__ unsigned short f2bf(float x) {
  unsigned int b = __float_as_uint(x);
  unsigned int r = (b + 0x7fffu + ((b >> 16) & 1u)) >> 16;
  return (unsigned short)r;
}
static __device__ __forceinline__ float b2f(unsigned short u) {
  return __uint_as_float(((unsigned int)u) << 16);
}

static __device__ __forceinline__ float warpMax(float v) {
#pragma unroll
  for (int o = 32; o >= 1; o >>= 1) v = fmaxf(v, __shfl_xor(v, o));
  return v;
}
static __device__ __forceinline__ float warpSum(float v) {
#pragma unroll
  for (int o = 32; o >= 1; o >>= 1) v += __shfl_xor(v, o);
  return v;
}

// ---------------------------------------------------------------------------
// k_prep: convert weights f32 -> bf16. kvw = [k_w(128 rows); v_w(128 rows)][256]
// ---------------------------------------------------------------------------
__global__ __launch_bounds__(256) void k_prep(
    const float* __restrict__ kw, const float* __restrict__ vw,
    const float* __restrict__ qw, const float* __restrict__ ow,
    unsigned short* __restrict__ kvw, unsigned short* __restrict__ qwb,
    unsigned short* __restrict__ owb)
{
  const int t = blockIdx.x * 256 + threadIdx.x;  // one float4 per thread
  float4 f;
  unsigned short* dst;
  if (t < 16384) {           // kv: 65536 elems
    f = (t < 8192) ? ((const float4*)kw)[t] : ((const float4*)vw)[t - 8192];
    dst = kvw + (size_t)t * 4;
  } else if (t < 20480) {    // q: 16384 elems
    const int i = t - 16384;
    f = ((const float4*)qw)[i];
    dst = qwb + (size_t)i * 4;
  } else {                   // out: 16384 elems
    const int i = t - 20480;
    f = ((const float4*)ow)[i];
    dst = owb + (size_t)i * 4;
  }
  ushort4 u;
  u.x = f2bf(f.x); u.y = f2bf(f.y); u.z = f2bf(f.z); u.w = f2bf(f.w);
  *(ushort4*)dst = u;
}

// ---------------------------------------------------------------------------
// k_gather: qin_bf[ng][128] = lidar[b][:][pix]  (8 lanes per token),
//           pix_ws[ng], hits atomic +1
// ---------------------------------------------------------------------------
__global__ __launch_bounds__(256) void k_gather(
    const float* __restrict__ lidar, const int* __restrict__ cidx,
    unsigned short* __restrict__ qin, int* __restrict__ pix_ws,
    float* __restrict__ hits)
{
  const int t = blockIdx.x * 256 + threadIdx.x;
  const int ng = t >> 3, l8 = t & 7;
  const int b = ng / NT;
  const int2 ij = *(const int2*)(cidx + (size_t)ng * 2);
  int ii = ij.x; ii = ii < 0 ? 0 : (ii > HH - 1 ? HH - 1 : ii);
  int jj = ij.y; jj = jj < 0 ? 0 : (jj > WWW - 1 ? WWW - 1 : jj);
  const int pix = ii * WWW + jj;
  if (l8 == 0) {
    pix_ws[ng] = pix;
    atomicAdd(hits + (size_t)b * HWHW + pix, 1.0f);
  }
  const float* src = lidar + ((size_t)b * CC + l8 * 16) * HWHW + pix;
  bf16x8 v0, v1;
#pragma unroll
  for (int c = 0; c < 8; ++c) v0[c] = (short)f2bf(src[(size_t)c * HWHW]);
#pragma unroll
  for (int c = 0; c < 8; ++c) v1[c] = (short)f2bf(src[(size_t)(c + 8) * HWHW]);
  unsigned short* dst = qin + (size_t)ng * 128 + l8 * 16;
  ((bf16x8*)dst)[0] = v0;
  ((bf16x8*)dst)[1] = v1;
}

// ---------------------------------------------------------------------------
// k_gemm: C[M=80000, NOUT] = A[M,K] * W[NOUT,K]^T   (bf16 MFMA 16x16x32)
// BM=BN=128, BK=64, 4 waves 2x2, each wave 64x64 (4x4 fragments).
// REGA: A is f32 (tokens), reg-staged with cvt. Else A bf16 via global_load_lds.
// EPI 0: store bf16 rows (+optional f32 bias). EPI 1: atomic-scatter f32 into
//        delta[B][HW][128] at pixel pix_ws[row].
// ---------------------------------------------------------------------------
template<int KSTEPS, int KW, bool REGA, int EPI, int NOUT>
__global__ __launch_bounds__(256) void k_gemm(
    const float* __restrict__ Af32, const unsigned short* __restrict__ Abf,
    const unsigned short* __restrict__ Bw, const float* __restrict__ bias,
    unsigned short* __restrict__ Dbf, const int* __restrict__ pix_ws,
    float* __restrict__ delta)
{
  __shared__ unsigned short lds[16384];  // A: [0,8192), B: [8192,16384) ushorts
  const int tid = threadIdx.x;
  const int lane = tid & 63, wave = tid >> 6;
  const int wm = wave >> 1, wn = wave & 1;
  const int mblk = blockIdx.x, nblk = blockIdx.y;
  const int l16 = lane & 15, kg = lane >> 4;

  const int grow0 = wave * 8 + (lane >> 3);   // + w2*32 per chunk
  const int gcol = (lane & 7) * 8;            // bf16/f32 index within 64-col tile

  f32x4 acc[4][4];
#pragma unroll
  for (int i = 0; i < 4; ++i)
#pragma unroll
    for (int j = 0; j < 4; ++j) acc[i][j] = (f32x4)0.0f;

  for (int kt = 0; kt < KSTEPS; ++kt) {
    __syncthreads();
    // ---- stage A ----
    if (REGA) {
#pragma unroll
      for (int w2 = 0; w2 < 4; ++w2) {
        const int r = w2 * 32 + grow0;
        const float* g = Af32 + (size_t)(mblk * 128 + r) * KW + kt * 64 + gcol;
        const float4 f0 = *(const float4*)g;
        const float4 f1 = *(const float4*)(g + 4);
        bf16x8 v;
        v[0] = (short)f2bf(f0.x); v[1] = (short)f2bf(f0.y);
        v[2] = (short)f2bf(f0.z); v[3] = (short)f2bf(f0.w);
        v[4] = (short)f2bf(f1.x); v[5] = (short)f2bf(f1.y);
        v[6] = (short)f2bf(f1.z); v[7] = (short)f2bf(f1.w);
        *(bf16x8*)&lds[w2 * 2048 + wave * 512 + lane * 8] = v;
      }
    } else {
#pragma unroll
      for (int w2 = 0; w2 < 4; ++w2) {
        const unsigned short* g =
            Abf + (size_t)(mblk * 128 + w2 * 32 + grow0) * KW + kt * 64 + gcol;
        gll16(g, &lds[w2 * 2048 + wave * 512]);
      }
    }
    // ---- stage B (weights, bf16) ----
#pragma unroll
    for (int w2 = 0; w2 < 4; ++w2) {
      const unsigned short* g =
          Bw + (size_t)(nblk * 128 + w2 * 32 + grow0) * KW + kt * 64 + gcol;
      gll16(g, &lds[8192 + w2 * 2048 + wave * 512]);
    }
    __syncthreads();
    // ---- MFMA ----
#pragma unroll
    for (int ks = 0; ks < 2; ++ks) {
      bf16x8 a[4], b[4];
#pragma unroll
      for (int mf = 0; mf < 4; ++mf)
        a[mf] = *(const bf16x8*)&lds[(wm * 64 + mf * 16 + l16) * 64 + ks * 32 + kg * 8];
#pragma unroll
      for (int nf = 0; nf < 4; ++nf)
        b[nf] = *(const bf16x8*)&lds[8192 + (wn * 64 + nf * 16 + l16) * 64 + ks * 32 + kg * 8];
#pragma unroll
      for (int mf = 0; mf < 4; ++mf)
#pragma unroll
        for (int nf = 0; nf < 4; ++nf)
          acc[mf][nf] = __builtin_amdgcn_mfma_f32_16x16x32_bf16(a[mf], b[nf], acc[mf][nf], 0, 0, 0);
    }
  }

  // ---- epilogue ----
  if constexpr (EPI == 0) {
    float bv[4];
#pragma unroll
    for (int nf = 0; nf < 4; ++nf) {
      const int colg = nblk * 128 + wn * 64 + nf * 16 + l16;
      bv[nf] = bias ? bias[colg] : 0.0f;
    }
#pragma unroll
    for (int mf = 0; mf < 4; ++mf) {
#pragma unroll
      for (int j = 0; j < 4; ++j) {
        const int row = mblk * 128 + wm * 64 + mf * 16 + kg * 4 + j;
        unsigned short* dr = Dbf + (size_t)row * NOUT + nblk * 128 + wn * 64 + l16;
#pragma unroll
        for (int nf = 0; nf < 4; ++nf)
          dr[nf * 16] = f2bf(acc[mf][nf][j] + bv[nf]);
      }
    }
  } else {
#pragma unroll
    for (int mf = 0; mf < 4; ++mf) {
#pragma unroll
      for (int j = 0; j < 4; ++j) {
        const int row = mblk * 128 + wm * 64 + mf * 16 + kg * 4 + j;
        const int pix = pix_ws[row];
        const int bb = row / NT;
        float* dr = delta + ((size_t)bb * HWHW + pix) * 128 + wn * 64 + l16;
#pragma unroll
        for (int nf = 0; nf < 4; ++nf)
          atomicAdd(dr + nf * 16, acc[mf][nf][j]);
      }
    }
  }
}

// ---------------------------------------------------------------------------
// k_logits: logits[b][h][n] = scale * sum_d qg[ng][h*32+d] * kv[ng][h*32+d]
// 8 lanes per token, 16 dims each, pair-reduce.
// ---------------------------------------------------------------------------
__global__ __launch_bounds__(256) void k_logits(
    const unsigned short* __restrict__ qg, const unsigned short* __restrict__ kv,
    float* __restrict__ logits)
{
  const int t = blockIdx.x * 256 + threadIdx.x;
  const int ng = t >> 3, l8 = t & 7;
  const int b = ng / NT, n = ng - b * NT;
  const bf16x8* qr = (const bf16x8*)(qg + (size_t)ng * 128 + l8 * 16);
  const bf16x8* kr = (const bf16x8*)(kv + (size_t)ng * 256 + l8 * 16);
  const bf16x8 q0 = qr[0], q1 = qr[1], k0 = kr[0], k1 = kr[1];
  float s = 0.0f;
#pragma unroll
  for (int e = 0; e < 8; ++e)
    s = fmaf(b2f((unsigned short)q0[e]), b2f((unsigned short)k0[e]), s);
#pragma unroll
  for (int e = 0; e < 8; ++e)
    s = fmaf(b2f((unsigned short)q1[e]), b2f((unsigned short)k1[e]), s);
  s += __shfl_xor(s, 1);
  if ((l8 & 1) == 0)
    logits[((size_t)b * NHEADS + (l8 >> 1)) * NT + n] = s * SCALE_C;
}

// ---------------------------------------------------------------------------
// k_softmax: softmax over N per (b,h), in-place, then * gate
// ---------------------------------------------------------------------------
__global__ __launch_bounds__(256) void k_softmax(
    float* __restrict__ logits, const float* __restrict__ gate)
{
  const int bh = blockIdx.x;
  const int b = bh / NHEADS;
  float* L = logits + (size_t)bh * NT;
  const float* g = gate + (size_t)b * NT;
  __shared__ float sred[4];
  const int tid = threadIdx.x;

  float m = -INFINITY;
  for (int i = tid; i < NT; i += 256) m = fmaxf(m, L[i]);
  m = warpMax(m);
  if ((tid & 63) == 0) sred[tid >> 6] = m;
  __syncthreads();
  m = fmaxf(fmaxf(sred[0], sred[1]), fmaxf(sred[2], sred[3]));

  float s = 0.0f;
  for (int i = tid; i < NT; i += 256) s += __expf(L[i] - m);
  s = warpSum(s);
  __syncthreads();
  if ((tid & 63) == 0) sred[tid >> 6] = s;
  __syncthreads();
  s = sred[0] + sred[1] + sred[2] + sred[3];
  const float inv = 1.0f / s;
  for (int i = tid; i < NT; i += 256) L[i] = __expf(L[i] - m) * inv * g[i];
}

// ---------------------------------------------------------------------------
// k_fused: fused_bf[ng][o] = kv[ng][128+o] * attn[b][o/32][n]
// ---------------------------------------------------------------------------
__global__ __launch_bounds__(256) void k_fused(
    const unsigned short* __restrict__ kv, const float* __restrict__ attn,
    unsigned short* __restrict__ fused)
{
  const int t = blockIdx.x * 256 + threadIdx.x;
  const int ng = t >> 3, l8 = t & 7;
  const int b = ng / NT, n = ng - b * NT;
  const float a = attn[((size_t)b * NHEADS + (l8 >> 1)) * NT + n];
  const bf16x8* vr = (const bf16x8*)(kv + (size_t)ng * 256 + 128 + l8 * 16);
  const bf16x8 v0 = vr[0], v1 = vr[1];
  bf16x8 o0, o1;
#pragma unroll
  for (int e = 0; e < 8; ++e) o0[e] = (short)f2bf(b2f((unsigned short)v0[e]) * a);
#pragma unroll
  for (int e = 0; e < 8; ++e) o1[e] = (short)f2bf(b2f((unsigned short)v1[e]) * a);
  unsigned short* dst = fused + (size_t)ng * 128 + l8 * 16;
  ((bf16x8*)dst)[0] = o0;
  ((bf16x8*)dst)[1] = o1;
}

// ---------------------------------------------------------------------------
// k_cnt: cnt[b] = number of hit pixels
// ---------------------------------------------------------------------------
__global__ __launch_bounds__(256) void k_cnt(
    const float* __restrict__ hits, float* __restrict__ cnt)
{
  const int b = blockIdx.x;
  const int tid = threadIdx.x;
  float s = 0.0f;
  for (int i = tid; i < HWHW; i += 256)
    s += (hits[(size_t)b * HWHW + i] > 0.0f) ? 1.0f : 0.0f;
  s = warpSum(s);
  __shared__ float sred[4];
  if ((tid & 63) == 0) sred[tid >> 6] = s;
  __syncthreads();
  if (tid == 0) cnt[b] = sred[0] + sred[1] + sred[2] + sred[3];
}

// ---------------------------------------------------------------------------
// k_mean: mean_raw[b][c] += column sums of delta[b][:][c]   (32400 = 100*324)
// ---------------------------------------------------------------------------
__global__ __launch_bounds__(256) void k_mean(
    const float* __restrict__ delta, float* __restrict__ mean_raw)
{
  const int b = blockIdx.y;
  const int c = threadIdx.x & 127, sub = threadIdx.x >> 7;
  const int p0 = blockIdx.x * 324;
  float acc = 0.0f;
  for (int i = sub; i < 324; i += 2)
    acc += delta[((size_t)b * HWHW + p0 + i) * 128 + c];
  atomicAdd(mean_raw + b * 128 + c, acc);
}

// ---------------------------------------------------------------------------
// k_final: out[b][c][hw] = lidar + (delta[b][hw][c] - mean*mask) * alpha * gamma
// 80-pixel x 128-channel tiles, transposed through padded LDS. 32400 = 405*80.
// ---------------------------------------------------------------------------
__global__ __launch_bounds__(256) void k_final(
    const float* __restrict__ lidar, const float* __restrict__ alpha,
    const float* __restrict__ hits, const float* __restrict__ mean_raw,
    const float* __restrict__ cnt, const float* __restrict__ delta,
    float* __restrict__ out)
{
  __shared__ float tile[80 * 129];
  const int b = blockIdx.y;
  const int p0 = blockIdx.x * 80;
  const int t = threadIdx.x;
#pragma unroll
  for (int i = 0; i < 10; ++i) {
    const int e = (t + i * 256) * 4;        // 80*128 = 10240 floats
    const int p = e >> 7, c = e & 127;
    const float4 f = *(const float4*)(delta + ((size_t)b * HWHW + p0 + p) * 128 + c);
    float* dst = &tile[p * 129 + c];
    dst[0] = f.x; dst[1] = f.y; dst[2] = f.z; dst[3] = f.w;
  }
  __syncthreads();
  const int c = t >> 1, half = t & 1;
  const float mn = mean_raw[b * 128 + c] / (cnt[b] + EPS_C);
  const size_t obase = ((size_t)b * CC + c) * HWHW + p0 + half * 40;
  for (int j = 0; j < 40; ++j) {
    const int p = half * 40 + j;
    const float d = tile[p * 129 + c];
    const float ht = hits[(size_t)b * HWHW + p0 + p];
    const float al = alpha[p0 + p];
    out[obase + j] = lidar[obase + j] + (d - (ht > 0.0f ? mn : 0.0f)) * al * GAMMA_C;
  }
}

// ---------------------------------------------------------------------------
extern "C" void kernel_launch(void* const* d_in, const int* in_sizes, int n_in,
                              void* d_out, int out_size, void* d_ws, size_t ws_size,
                              hipStream_t stream)
{
  const float* lidar  = (const float*)d_in[0];
  const float* tokens = (const float*)d_in[1];
  const float* gate   = (const float*)d_in[2];
  const float* alpha  = (const float*)d_in[3];
  const float* q_w    = (const float*)d_in[4];
  const float* q_b    = (const float*)d_in[5];
  const float* k_w    = (const float*)d_in[6];
  const float* v_w    = (const float*)d_in[7];
  const float* out_w  = (const float*)d_in[8];
  const int*   cidx   = (const int*)d_in[9];
  float* out = (float*)d_out;

  char* W = (char*)d_ws;
  // kv_bf [80000][256] bf16 : 40,960,000 B
  unsigned short* kv_bf = (unsigned short*)(W + 0);
  // X region (qin_bf, later fused_bf) [80000][128] bf16 : 20,480,000 B
  unsigned short* qin_bf   = (unsigned short*)(W + 40960000);
  unsigned short* fused_bf = qin_bf;
  // delta [B][HW][128] f32 : 66,355,200 B   (qg_bf aliases its head; qg is
  // dead before the delta memset)
  float* delta = (float*)(W + 61440000);
  unsigned short* qg_bf = (unsigned short*)(W + 61440000);
  float* logits   = (float*)(W + 127795200);   // 1,280,000 B
  int*   pix_ws   = (int*)(W + 129075200);     //   320,000 B
  float* hits     = (float*)(W + 129395200);   //   518,400 B
  float* mean_raw = (float*)(W + 129913600);   //     2,048 B
  float* cnt      = (float*)(W + 129915648);   //        64 B
  unsigned short* kvw_bf = (unsigned short*)(W + 129915712);  // 131,072 B
  unsigned short* qw_bf  = (unsigned short*)(W + 130046784);  //  32,768 B
  unsigned short* ow_bf  = (unsigned short*)(W + 130079552);  //  32,768 B

  hipMemsetAsync(hits, 0, (size_t)BB * HWHW * sizeof(float), stream);
  hipMemsetAsync(mean_raw, 0, 2048 + 64, stream);

  k_prep<<<dim3(96), 256, 0, stream>>>(k_w, v_w, q_w, out_w, kvw_bf, qw_bf, ow_bf);
  k_gather<<<dim3(2500), 256, 0, stream>>>(lidar, cidx, qin_bf, pix_ws, hits);
  // kv projection: [80000,256] x [256,256]^T
  k_gemm<4, 256, true, 0, 256><<<dim3(625, 2), 256, 0, stream>>>(
      tokens, nullptr, kvw_bf, nullptr, kv_bf, nullptr, nullptr);
  // q projection: [80000,128] x [128,128]^T + bias
  k_gemm<2, 128, false, 0, 128><<<dim3(625, 1), 256, 0, stream>>>(
      nullptr, qin_bf, qw_bf, q_b, qg_bf, nullptr, nullptr);
  k_logits<<<dim3(2500), 256, 0, stream>>>(qg_bf, kv_bf, logits);
  hipMemsetAsync(delta, 0, (size_t)BB * HWHW * 128 * sizeof(float), stream);
  k_softmax<<<dim3(BB * NHEADS), 256, 0, stream>>>(logits, gate);
  k_fused<<<dim3(2500), 256, 0, stream>>>(kv_bf, logits, fused_bf);
  // out projection + scatter: [80000,128] x [128,128]^T -> delta[B][HW][128]
  k_gemm<2, 128, false, 1, 128><<<dim3(625, 1), 256, 0, stream>>>(
      nullptr, fused_bf, ow_bf, nullptr, nullptr, pix_ws, delta);
  k_cnt<<<dim3(BB), 256, 0, stream>>>(hits, cnt);
  k_mean<<<dim3(100, BB), 256, 0, stream>>>(delta, mean_raw);
  k_final<<<dim3(405, BB), 256, 0, stream>>>(lidar, alpha, hits, mean_raw, cnt,
                                             delta, out);
}

// Round 3
// 316.158 us; speedup vs baseline: 5.2416x; 1.4775x over previous
//
#include <hip/hip_runtime.h>

#define BB 4
#define CC 128
#define HH 180
#define WWW 180
#define HWHW (HH*WWW)       // 32400
#define CCAMD 256
#define NHEADS 4
#define HDD 128
#define NT 20000
#define MTOT 80000          // B*N, = 625 * 128 exactly
#define GAMMA_C 0.08f
#define EPS_C 1e-6f
#define SCALE_C 0.17677669529663687f  // 1/sqrt(32)

typedef short bf16x8 __attribute__((ext_vector_type(8)));
typedef float f32x4 __attribute__((ext_vector_type(4)));

typedef __attribute__((address_space(1))) const unsigned int GU;
typedef __attribute__((address_space(3))) unsigned int LU;

static __device__ __forceinline__ void gll16(const void* g, void* l) {
  __builtin_amdgcn_global_load_lds((GU*)g, (LU*)l, 16, 0, 0);
}

static __device__ __forceinline__ unsigned short f2bf(float x) {
  unsigned int b = __float_as_uint(x);
  unsigned int r = (b + 0x7fffu + ((b >> 16) & 1u)) >> 16;
  return (unsigned short)r;
}
static __device__ __forceinline__ float b2f(unsigned short u) {
  return __uint_as_float(((unsigned int)u) << 16);
}

static __device__ __forceinline__ float warpMax(float v) {
#pragma unroll
  for (int o = 32; o >= 1; o >>= 1) v = fmaxf(v, __shfl_xor(v, o));
  return v;
}
static __device__ __forceinline__ float warpSum(float v) {
#pragma unroll
  for (int o = 32; o >= 1; o >>= 1) v += __shfl_xor(v, o);
  return v;
}

// ---------------------------------------------------------------------------
// k_prep: convert weights f32 -> bf16. kvw = [k_w(128 rows); v_w(128 rows)][256]
// ---------------------------------------------------------------------------
__global__ __launch_bounds__(256) void k_prep(
    const float* __restrict__ kw, const float* __restrict__ vw,
    const float* __restrict__ qw, const float* __restrict__ ow,
    unsigned short* __restrict__ kvw, unsigned short* __restrict__ qwb,
    unsigned short* __restrict__ owb)
{
  const int t = blockIdx.x * 256 + threadIdx.x;  // one float4 per thread
  float4 f;
  unsigned short* dst;
  if (t < 16384) {           // kv: 65536 elems
    f = (t < 8192) ? ((const float4*)kw)[t] : ((const float4*)vw)[t - 8192];
    dst = kvw + (size_t)t * 4;
  } else if (t < 20480) {    // q: 16384 elems
    const int i = t - 16384;
    f = ((const float4*)qw)[i];
    dst = qwb + (size_t)i * 4;
  } else {                   // out: 16384 elems
    const int i = t - 20480;
    f = ((const float4*)ow)[i];
    dst = owb + (size_t)i * 4;
  }
  ushort4 u;
  u.x = f2bf(f.x); u.y = f2bf(f.y); u.z = f2bf(f.z); u.w = f2bf(f.w);
  *(ushort4*)dst = u;
}

// ---------------------------------------------------------------------------
// k_pix: pix_ws[ng] = clamped linear pixel; hits[b][pix] += 1
// ---------------------------------------------------------------------------
__global__ __launch_bounds__(256) void k_pix(
    const int* __restrict__ cidx, int* __restrict__ pix_ws,
    float* __restrict__ hits)
{
  const int t = blockIdx.x * 256 + threadIdx.x;
  if (t >= MTOT) return;
  const int2 ij = *(const int2*)(cidx + (size_t)t * 2);
  int ii = ij.x; ii = ii < 0 ? 0 : (ii > HH - 1 ? HH - 1 : ii);
  int jj = ij.y; jj = jj < 0 ? 0 : (jj > WWW - 1 ? WWW - 1 : jj);
  const int pix = ii * WWW + jj;
  pix_ws[t] = pix;
  atomicAdd(hits + (size_t)(t / NT) * HWHW + pix, 1.0f);
}

// ---------------------------------------------------------------------------
// k_tr2: lidar_t[b][p][c] (bf16) = lidar[b][c][p].  One pixel per lane,
// coalesced channel-row reads; each lane fully covers its 256B output row.
// blockIdx.z splits channels in halves for occupancy.
// ---------------------------------------------------------------------------
__global__ __launch_bounds__(256) void k_tr2(
    const float* __restrict__ lidar, unsigned short* __restrict__ lidar_t)
{
  const int b = blockIdx.y;
  const int p = blockIdx.x * 256 + threadIdx.x;
  if (p >= HWHW) return;
  const int z = blockIdx.z;  // channel half
  const float* src = lidar + ((size_t)b * CC + z * 64) * HWHW + p;
  unsigned short* dst = lidar_t + ((size_t)b * HWHW + p) * 128 + z * 64;
#pragma unroll
  for (int c8 = 0; c8 < 8; ++c8) {
    bf16x8 v;
#pragma unroll
    for (int e = 0; e < 8; ++e)
      v[e] = (short)f2bf(src[(size_t)(c8 * 8 + e) * HWHW]);
    ((bf16x8*)dst)[c8] = v;
  }
}

// ---------------------------------------------------------------------------
// k_gemm: C[M=80000, NOUT] = A[M,K] * W[NOUT,K]^T   (bf16 MFMA 16x16x32)
// BM=BN=128, BK=64, 4 waves 2x2, each wave 64x64 (4x4 fragments).
// AMODE 0: A f32, reg-staged+cvt (tokens). AMODE 1: A bf16 rows via gll16.
// AMODE 2: A bf16 rows gathered from lidar_t via pix_ws.
// LDS tiles XOR-swizzled (c8 ^= row&7) on the source side (rule #21);
// MFMA ds_read uses matching swizzle -> 2-way banks instead of 16-way.
// EPI 0: store bf16 rows (+opt f32 bias). EPI 1: atomic f32 scatter into
//        delta[B][HW][128] at pix_ws[row].
// ---------------------------------------------------------------------------
template<int KSTEPS, int KW, int AMODE, int EPI, int NOUT>
__global__ __launch_bounds__(256) void k_gemm(
    const float* __restrict__ Af32, const unsigned short* __restrict__ Abf,
    const unsigned short* __restrict__ Bw, const float* __restrict__ bias,
    unsigned short* __restrict__ Dbf, const int* __restrict__ pixw,
    float* __restrict__ delta)
{
  __shared__ unsigned short lds[16384];  // A: [0,8192), B: [8192,16384)
  const int tid = threadIdx.x;
  const int lane = tid & 63, wave = tid >> 6;
  const int wm = wave >> 1, wn = wave & 1;
  const int mblk = blockIdx.x, nblk = blockIdx.y;
  const int l16 = lane & 15, kg = lane >> 4;

  const int g3 = lane >> 3;        // row within 8-row group (== lds_row & 7)
  const int c8l = lane & 7;
  const int grow0 = wave * 8 + g3;
  const int gcol_lin = c8l * 8;
  const int gcol_swz = (c8l ^ g3) * 8;

  f32x4 acc[4][4];
#pragma unroll
  for (int i = 0; i < 4; ++i)
#pragma unroll
    for (int j = 0; j < 4; ++j) acc[i][j] = (f32x4)0.0f;

  const unsigned short* arow[4];
  if constexpr (AMODE == 2) {
#pragma unroll
    for (int w2 = 0; w2 < 4; ++w2) {
      const int r = mblk * 128 + w2 * 32 + grow0;
      const int bb = r / NT;
      const int pix = pixw[r];
      arow[w2] = Abf + ((size_t)bb * HWHW + pix) * 128 + gcol_swz;
    }
  }

  for (int kt = 0; kt < KSTEPS; ++kt) {
    __syncthreads();
    // ---- stage A ----
    if constexpr (AMODE == 0) {
#pragma unroll
      for (int w2 = 0; w2 < 4; ++w2) {
        const int r = w2 * 32 + grow0;
        const float* g = Af32 + (size_t)(mblk * 128 + r) * KW + kt * 64 + gcol_lin;
        const float4 f0 = *(const float4*)g;
        const float4 f1 = *(const float4*)(g + 4);
        bf16x8 v;
        v[0] = (short)f2bf(f0.x); v[1] = (short)f2bf(f0.y);
        v[2] = (short)f2bf(f0.z); v[3] = (short)f2bf(f0.w);
        v[4] = (short)f2bf(f1.x); v[5] = (short)f2bf(f1.y);
        v[6] = (short)f2bf(f1.z); v[7] = (short)f2bf(f1.w);
        *(bf16x8*)&lds[w2 * 2048 + wave * 512 + g3 * 64 + gcol_swz] = v;
      }
    } else if constexpr (AMODE == 1) {
#pragma unroll
      for (int w2 = 0; w2 < 4; ++w2) {
        const unsigned short* g =
            Abf + (size_t)(mblk * 128 + w2 * 32 + grow0) * KW + kt * 64 + gcol_swz;
        gll16(g, &lds[w2 * 2048 + wave * 512]);
      }
    } else {
#pragma unroll
      for (int w2 = 0; w2 < 4; ++w2)
        gll16(arow[w2] + kt * 64, &lds[w2 * 2048 + wave * 512]);
    }
    // ---- stage B (weights) ----
#pragma unroll
    for (int w2 = 0; w2 < 4; ++w2) {
      const unsigned short* g =
          Bw + (size_t)(nblk * 128 + w2 * 32 + grow0) * KW + kt * 64 + gcol_swz;
      gll16(g, &lds[8192 + w2 * 2048 + wave * 512]);
    }
    __syncthreads();
    // ---- MFMA ----
#pragma unroll
    for (int ks = 0; ks < 2; ++ks) {
      const int swz = ((ks * 4 + kg) ^ (l16 & 7)) * 8;
      bf16x8 a[4], b[4];
#pragma unroll
      for (int mf = 0; mf < 4; ++mf)
        a[mf] = *(const bf16x8*)&lds[(wm * 64 + mf * 16 + l16) * 64 + swz];
#pragma unroll
      for (int nf = 0; nf < 4; ++nf)
        b[nf] = *(const bf16x8*)&lds[8192 + (wn * 64 + nf * 16 + l16) * 64 + swz];
#pragma unroll
      for (int mf = 0; mf < 4; ++mf)
#pragma unroll
        for (int nf = 0; nf < 4; ++nf)
          acc[mf][nf] = __builtin_amdgcn_mfma_f32_16x16x32_bf16(a[mf], b[nf], acc[mf][nf], 0, 0, 0);
    }
  }

  // ---- epilogue ----
  if constexpr (EPI == 0) {
    float bv[4];
#pragma unroll
    for (int nf = 0; nf < 4; ++nf) {
      const int colg = nblk * 128 + wn * 64 + nf * 16 + l16;
      bv[nf] = bias ? bias[colg] : 0.0f;
    }
#pragma unroll
    for (int mf = 0; mf < 4; ++mf) {
#pragma unroll
      for (int j = 0; j < 4; ++j) {
        const int row = mblk * 128 + wm * 64 + mf * 16 + kg * 4 + j;
        unsigned short* dr = Dbf + (size_t)row * NOUT + nblk * 128 + wn * 64 + l16;
#pragma unroll
        for (int nf = 0; nf < 4; ++nf)
          dr[nf * 16] = f2bf(acc[mf][nf][j] + bv[nf]);
      }
    }
  } else {
#pragma unroll
    for (int mf = 0; mf < 4; ++mf) {
#pragma unroll
      for (int j = 0; j < 4; ++j) {
        const int row = mblk * 128 + wm * 64 + mf * 16 + kg * 4 + j;
        const int pix = pixw[row];
        const int bb = row / NT;
        float* dr = delta + ((size_t)bb * HWHW + pix) * 128 + wn * 64 + l16;
#pragma unroll
        for (int nf = 0; nf < 4; ++nf)
          atomicAdd(dr + nf * 16, acc[mf][nf][j]);
      }
    }
  }
}

// ---------------------------------------------------------------------------
// k_logits: logits[b][h][n] = scale * sum_d qg[ng][h*32+d] * kv[ng][h*32+d]
// ---------------------------------------------------------------------------
__global__ __launch_bounds__(256) void k_logits(
    const unsigned short* __restrict__ qg, const unsigned short* __restrict__ kv,
    float* __restrict__ logits)
{
  const int t = blockIdx.x * 256 + threadIdx.x;
  const int ng = t >> 3, l8 = t & 7;
  const int b = ng / NT, n = ng - b * NT;
  const bf16x8* qr = (const bf16x8*)(qg + (size_t)ng * 128 + l8 * 16);
  const bf16x8* kr = (const bf16x8*)(kv + (size_t)ng * 256 + l8 * 16);
  const bf16x8 q0 = qr[0], q1 = qr[1], k0 = kr[0], k1 = kr[1];
  float s = 0.0f;
#pragma unroll
  for (int e = 0; e < 8; ++e)
    s = fmaf(b2f((unsigned short)q0[e]), b2f((unsigned short)k0[e]), s);
#pragma unroll
  for (int e = 0; e < 8; ++e)
    s = fmaf(b2f((unsigned short)q1[e]), b2f((unsigned short)k1[e]), s);
  s += __shfl_xor(s, 1);
  if ((l8 & 1) == 0)
    logits[((size_t)b * NHEADS + (l8 >> 1)) * NT + n] = s * SCALE_C;
}

// ---------------------------------------------------------------------------
// k_smpart: per-(bh, chunk) partial max & sum-exp.  NT = 8 * 2500.
// ---------------------------------------------------------------------------
__global__ __launch_bounds__(256) void k_smpart(
    const float* __restrict__ logits, float* __restrict__ pm,
    float* __restrict__ ps)
{
  const int ch = blockIdx.x, bh = blockIdx.y;
  const float* L = logits + (size_t)bh * NT + ch * 2500;
  const int tid = threadIdx.x;
  __shared__ float sred[4];

  float m = -INFINITY;
  for (int i = tid; i < 2500; i += 256) m = fmaxf(m, L[i]);
  m = warpMax(m);
  if ((tid & 63) == 0) sred[tid >> 6] = m;
  __syncthreads();
  m = fmaxf(fmaxf(sred[0], sred[1]), fmaxf(sred[2], sred[3]));

  float s = 0.0f;
  for (int i = tid; i < 2500; i += 256) s += __expf(L[i] - m);
  s = warpSum(s);
  __syncthreads();
  if ((tid & 63) == 0) sred[tid >> 6] = s;
  __syncthreads();
  if (tid == 0) {
    pm[bh * 8 + ch] = m;
    ps[bh * 8 + ch] = sred[0] + sred[1] + sred[2] + sred[3];
  }
}

// ---------------------------------------------------------------------------
// k_smfix: combine partials -> smM[bh], smSinv[bh]
// ---------------------------------------------------------------------------
__global__ void k_smfix(const float* __restrict__ pm, const float* __restrict__ ps,
                        float* __restrict__ smM, float* __restrict__ smSinv)
{
  const int bh = threadIdx.x;
  if (bh >= BB * NHEADS) return;
  float M = -INFINITY;
#pragma unroll
  for (int c = 0; c < 8; ++c) M = fmaxf(M, pm[bh * 8 + c]);
  float S = 0.0f;
#pragma unroll
  for (int c = 0; c < 8; ++c) S += ps[bh * 8 + c] * __expf(pm[bh * 8 + c] - M);
  smM[bh] = M;
  smSinv[bh] = 1.0f / S;
}

// ---------------------------------------------------------------------------
// k_fused: fused_bf[ng][o] = v[ng][o] * softmax(logit)*gate
// ---------------------------------------------------------------------------
__global__ __launch_bounds__(256) void k_fused(
    const unsigned short* __restrict__ kv, const float* __restrict__ logits,
    const float* __restrict__ smM, const float* __restrict__ smSinv,
    const float* __restrict__ gate, unsigned short* __restrict__ fused)
{
  const int t = blockIdx.x * 256 + threadIdx.x;
  const int ng = t >> 3, l8 = t & 7;
  const int b = ng / NT, n = ng - b * NT;
  const int bh = b * NHEADS + (l8 >> 1);
  const float l = logits[(size_t)bh * NT + n];
  const float a = __expf(l - smM[bh]) * smSinv[bh] * gate[(size_t)b * NT + n];
  const bf16x8* vr = (const bf16x8*)(kv + (size_t)ng * 256 + 128 + l8 * 16);
  const bf16x8 v0 = vr[0], v1 = vr[1];
  bf16x8 o0, o1;
#pragma unroll
  for (int e = 0; e < 8; ++e) o0[e] = (short)f2bf(b2f((unsigned short)v0[e]) * a);
#pragma unroll
  for (int e = 0; e < 8; ++e) o1[e] = (short)f2bf(b2f((unsigned short)v1[e]) * a);
  unsigned short* dst = fused + (size_t)ng * 128 + l8 * 16;
  ((bf16x8*)dst)[0] = o0;
  ((bf16x8*)dst)[1] = o1;
}

// ---------------------------------------------------------------------------
// k_cnt: cnt[b] = number of hit pixels
// ---------------------------------------------------------------------------
__global__ __launch_bounds__(256) void k_cnt(
    const float* __restrict__ hits, float* __restrict__ cnt)
{
  const int b = blockIdx.x;
  const int tid = threadIdx.x;
  float s = 0.0f;
  for (int i = tid; i < HWHW; i += 256)
    s += (hits[(size_t)b * HWHW + i] > 0.0f) ? 1.0f : 0.0f;
  s = warpSum(s);
  __shared__ float sred[4];
  if ((tid & 63) == 0) sred[tid >> 6] = s;
  __syncthreads();
  if (tid == 0) cnt[b] = sred[0] + sred[1] + sred[2] + sred[3];
}

// ---------------------------------------------------------------------------
// k_mean: mean_raw[b][c] += column sums of delta[b][:][c]   (32400 = 100*324)
// ---------------------------------------------------------------------------
__global__ __launch_bounds__(256) void k_mean(
    const float* __restrict__ delta, float* __restrict__ mean_raw)
{
  const int b = blockIdx.y;
  const int c = threadIdx.x & 127, sub = threadIdx.x >> 7;
  const int p0 = blockIdx.x * 324;
  float acc = 0.0f;
  for (int i = sub; i < 324; i += 2)
    acc += delta[((size_t)b * HWHW + p0 + i) * 128 + c];
  atomicAdd(mean_raw + b * 128 + c, acc);
}

// ---------------------------------------------------------------------------
// k_final: out[b][c][hw] = lidar + (delta[b][hw][c] - mean*mask)*alpha*gamma
// ---------------------------------------------------------------------------
__global__ __launch_bounds__(256) void k_final(
    const float* __restrict__ lidar, const float* __restrict__ alpha,
    const float* __restrict__ hits, const float* __restrict__ mean_raw,
    const float* __restrict__ cnt, const float* __restrict__ delta,
    float* __restrict__ out)
{
  __shared__ float tile[80 * 129];
  const int b = blockIdx.y;
  const int p0 = blockIdx.x * 80;
  const int t = threadIdx.x;
#pragma unroll
  for (int i = 0; i < 10; ++i) {
    const int e = (t + i * 256) * 4;        // 80*128 = 10240 floats
    const int p = e >> 7, c = e & 127;
    const float4 f = *(const float4*)(delta + ((size_t)b * HWHW + p0 + p) * 128 + c);
    float* dst = &tile[p * 129 + c];
    dst[0] = f.x; dst[1] = f.y; dst[2] = f.z; dst[3] = f.w;
  }
  __syncthreads();
  const int c = t >> 1, half = t & 1;
  const float mn = mean_raw[b * 128 + c] / (cnt[b] + EPS_C);
  const size_t obase = ((size_t)b * CC + c) * HWHW + p0 + half * 40;
  for (int j = 0; j < 40; ++j) {
    const int p = half * 40 + j;
    const float d = tile[p * 129 + c];
    const float ht = hits[(size_t)b * HWHW + p0 + p];
    const float al = alpha[p0 + p];
    out[obase + j] = lidar[obase + j] + (d - (ht > 0.0f ? mn : 0.0f)) * al * GAMMA_C;
  }
}

// ---------------------------------------------------------------------------
extern "C" void kernel_launch(void* const* d_in, const int* in_sizes, int n_in,
                              void* d_out, int out_size, void* d_ws, size_t ws_size,
                              hipStream_t stream)
{
  const float* lidar  = (const float*)d_in[0];
  const float* tokens = (const float*)d_in[1];
  const float* gate   = (const float*)d_in[2];
  const float* alpha  = (const float*)d_in[3];
  const float* q_w    = (const float*)d_in[4];
  const float* q_b    = (const float*)d_in[5];
  const float* k_w    = (const float*)d_in[6];
  const float* v_w    = (const float*)d_in[7];
  const float* out_w  = (const float*)d_in[8];
  const int*   cidx   = (const int*)d_in[9];
  float* out = (float*)d_out;

  char* W = (char*)d_ws;
  // kv_bf [80000][256] bf16
  unsigned short* kv_bf = (unsigned short*)(W + 0);                 // 40,960,000
  // fused_bf [80000][128] bf16
  unsigned short* fused_bf = (unsigned short*)(W + 40960000);       // 20,480,000
  // delta [B][HW][128] f32 (66,355,200). Until its memset this region also
  // hosts qg_bf (head, 20,480,000) and lidar_t (at +20,480,000; 33,177,600) —
  // both dead before the memset.
  float* delta = (float*)(W + 61440000);
  unsigned short* qg_bf   = (unsigned short*)(W + 61440000);
  unsigned short* lidar_t = (unsigned short*)(W + 81920000);
  float* logits   = (float*)(W + 127795200);   // 1,280,000
  int*   pix_ws   = (int*)(W + 129075200);     //   320,000
  float* hits     = (float*)(W + 129395200);   //   518,400
  float* mean_raw = (float*)(W + 129913600);   //     2,048
  float* cnt      = (float*)(W + 129915648);   //        64
  unsigned short* kvw_bf = (unsigned short*)(W + 129915712);  // 131,072
  unsigned short* qw_bf  = (unsigned short*)(W + 130046784);  //  32,768
  unsigned short* ow_bf  = (unsigned short*)(W + 130079552);  //  32,768
  float* pm     = (float*)(W + 130112320);     // 512
  float* ps     = (float*)(W + 130112832);     // 512
  float* smM    = (float*)(W + 130113344);     // 64
  float* smSinv = (float*)(W + 130113408);     // 64

  hipMemsetAsync(hits, 0, (size_t)BB * HWHW * sizeof(float), stream);
  hipMemsetAsync(mean_raw, 0, 2048 + 64, stream);

  k_prep<<<dim3(96), 256, 0, stream>>>(k_w, v_w, q_w, out_w, kvw_bf, qw_bf, ow_bf);
  k_pix<<<dim3(313), 256, 0, stream>>>(cidx, pix_ws, hits);
  k_tr2<<<dim3(127, BB, 2), 256, 0, stream>>>(lidar, lidar_t);
  // kv projection: [80000,256] x [256,256]^T
  k_gemm<4, 256, 0, 0, 256><<<dim3(625, 2), 256, 0, stream>>>(
      tokens, nullptr, kvw_bf, nullptr, kv_bf, nullptr, nullptr);
  // q projection with row gather from lidar_t: [80000,128] x [128,128]^T + bias
  k_gemm<2, 128, 2, 0, 128><<<dim3(625, 1), 256, 0, stream>>>(
      nullptr, lidar_t, qw_bf, q_b, qg_bf, pix_ws, nullptr);
  k_logits<<<dim3(2500), 256, 0, stream>>>(qg_bf, kv_bf, logits);
  // qg_bf / lidar_t dead from here
  hipMemsetAsync(delta, 0, (size_t)BB * HWHW * 128 * sizeof(float), stream);
  k_smpart<<<dim3(8, BB * NHEADS), 256, 0, stream>>>(logits, pm, ps);
  k_smfix<<<dim3(1), 64, 0, stream>>>(pm, ps, smM, smSinv);
  k_fused<<<dim3(2500), 256, 0, stream>>>(kv_bf, logits, smM, smSinv, gate, fused_bf);
  // out projection + scatter: [80000,128] x [128,128]^T -> delta[B][HW][128]
  k_gemm<2, 128, 1, 1, 128><<<dim3(625, 1), 256, 0, stream>>>(
      nullptr, fused_bf, ow_bf, nullptr, nullptr, pix_ws, delta);
  k_cnt<<<dim3(BB), 256, 0, stream>>>(hits, cnt);
  k_mean<<<dim3(100, BB), 256, 0, stream>>>(delta, mean_raw);
  k_final<<<dim3(405, BB), 256, 0, stream>>>(lidar, alpha, hits, mean_raw, cnt,
                                             delta, out);
}

// Round 4
// 258.996 us; speedup vs baseline: 6.3985x; 1.2207x over previous
//
#include <hip/hip_runtime.h>

#define BB 4
#define CC 128
#define HH 180
#define WWW 180
#define HWHW (HH*WWW)       // 32400
#define CCAMD 256
#define NHEADS 4
#define HDD 128
#define NT 20000
#define MTOT 80000          // B*N, = 625 * 128 exactly
#define GAMMA_C 0.08f
#define EPS_C 1e-6f
#define SCALE_C 0.17677669529663687f  // 1/sqrt(32)

typedef short bf16x8 __attribute__((ext_vector_type(8)));
typedef float f32x4 __attribute__((ext_vector_type(4)));

typedef __attribute__((address_space(1))) const unsigned int GU;
typedef __attribute__((address_space(3))) unsigned int LU;

static __device__ __forceinline__ void gll16(const void* g, void* l) {
  __builtin_amdgcn_global_load_lds((GU*)g, (LU*)l, 16, 0, 0);
}

static __device__ __forceinline__ unsigned short f2bf(float x) {
  unsigned int b = __float_as_uint(x);
  unsigned int r = (b + 0x7fffu + ((b >> 16) & 1u)) >> 16;
  return (unsigned short)r;
}
static __device__ __forceinline__ float b2f(unsigned short u) {
  return __uint_as_float(((unsigned int)u) << 16);
}

static __device__ __forceinline__ float warpMax(float v) {
#pragma unroll
  for (int o = 32; o >= 1; o >>= 1) v = fmaxf(v, __shfl_xor(v, o));
  return v;
}
static __device__ __forceinline__ float warpSum(float v) {
#pragma unroll
  for (int o = 32; o >= 1; o >>= 1) v += __shfl_xor(v, o);
  return v;
}

// ---------------------------------------------------------------------------
// k_prep_pix: blocks 0..95: weight f32->bf16; blocks 96..408: pixel indices.
// ---------------------------------------------------------------------------
__global__ __launch_bounds__(256) void k_prep_pix(
    const float* __restrict__ kw, const float* __restrict__ vw,
    const float* __restrict__ qw, const float* __restrict__ ow,
    unsigned short* __restrict__ kvw, unsigned short* __restrict__ qwb,
    unsigned short* __restrict__ owb, const int* __restrict__ cidx,
    int* __restrict__ pix_ws, float* __restrict__ hits)
{
  if (blockIdx.x < 96) {
    const int t = blockIdx.x * 256 + threadIdx.x;  // one float4 per thread
    float4 f;
    unsigned short* dst;
    if (t < 16384) {           // kv: 65536 elems
      f = (t < 8192) ? ((const float4*)kw)[t] : ((const float4*)vw)[t - 8192];
      dst = kvw + (size_t)t * 4;
    } else if (t < 20480) {    // q: 16384 elems
      const int i = t - 16384;
      f = ((const float4*)qw)[i];
      dst = qwb + (size_t)i * 4;
    } else {                   // out: 16384 elems
      const int i = t - 20480;
      f = ((const float4*)ow)[i];
      dst = owb + (size_t)i * 4;
    }
    ushort4 u;
    u.x = f2bf(f.x); u.y = f2bf(f.y); u.z = f2bf(f.z); u.w = f2bf(f.w);
    *(ushort4*)dst = u;
  } else {
    const int t = (blockIdx.x - 96) * 256 + threadIdx.x;
    if (t >= MTOT) return;
    const int2 ij = *(const int2*)(cidx + (size_t)t * 2);
    int ii = ij.x; ii = ii < 0 ? 0 : (ii > HH - 1 ? HH - 1 : ii);
    int jj = ij.y; jj = jj < 0 ? 0 : (jj > WWW - 1 ? WWW - 1 : jj);
    const int pix = ii * WWW + jj;
    pix_ws[t] = pix;
    atomicAdd(hits + (size_t)(t / NT) * HWHW + pix, 1.0f);
  }
}

// ---------------------------------------------------------------------------
// k_tr2: lidar_t[b][p][c] (bf16) = lidar[b][c][p].
// ---------------------------------------------------------------------------
__global__ __launch_bounds__(256) void k_tr2(
    const float* __restrict__ lidar, unsigned short* __restrict__ lidar_t)
{
  const int b = blockIdx.y;
  const int p = blockIdx.x * 256 + threadIdx.x;
  if (p >= HWHW) return;
  const int z = blockIdx.z;  // channel half
  const float* src = lidar + ((size_t)b * CC + z * 64) * HWHW + p;
  unsigned short* dst = lidar_t + ((size_t)b * HWHW + p) * 128 + z * 64;
#pragma unroll
  for (int c8 = 0; c8 < 8; ++c8) {
    bf16x8 v;
#pragma unroll
    for (int e = 0; e < 8; ++e)
      v[e] = (short)f2bf(src[(size_t)(c8 * 8 + e) * HWHW]);
    ((bf16x8*)dst)[c8] = v;
  }
}

// ---------------------------------------------------------------------------
// k_gemm: C[M=80000, NOUT] = A[M,K] * W[NOUT,K]^T   (bf16 MFMA 16x16x32)
// BM=BN=128, BK=64, 4 waves 2x2, each wave 64x64 (4x4 fragments).
// AMODE 0: A f32 reg-staged+cvt. AMODE 1: A bf16 rows via gll16.
// AMODE 2: A bf16 rows gathered from lidar_t via pixw.
// LDS XOR-swizzled on the source side; matching swizzle on ds_read.
// EPI 0: store bf16 rows (+opt bias).
// EPI 1: atomic f32 scatter into delta[B][HW][128] at pixw[row], plus
//        block-level column sums -> atomicAdd into meanr[b][c].
// EPI 2: per-head logits: logit[b,h,n] = SCALE * sum_d (acc+bias)*k  (k=kvb).
// ---------------------------------------------------------------------------
template<int KSTEPS, int KW, int AMODE, int EPI, int NOUT>
__global__ __launch_bounds__(256) void k_gemm(
    const float* __restrict__ Af32, const unsigned short* __restrict__ Abf,
    const unsigned short* __restrict__ Bw, const float* __restrict__ bias,
    unsigned short* __restrict__ Dbf, const int* __restrict__ pixw,
    float* __restrict__ aux,            // EPI1: delta; EPI2: logits
    const unsigned short* __restrict__ kvb, float* __restrict__ meanr)
{
  __shared__ unsigned short lds[16384];  // A: [0,8192), B: [8192,16384)
  const int tid = threadIdx.x;
  const int lane = tid & 63, wave = tid >> 6;
  const int wm = wave >> 1, wn = wave & 1;
  const int mblk = blockIdx.x, nblk = blockIdx.y;
  const int l16 = lane & 15, kg = lane >> 4;

  const int g3 = lane >> 3;        // row within 8-row group (== lds_row & 7)
  const int c8l = lane & 7;
  const int grow0 = wave * 8 + g3;
  const int gcol_lin = c8l * 8;
  const int gcol_swz = (c8l ^ g3) * 8;

  f32x4 acc[4][4];
#pragma unroll
  for (int i = 0; i < 4; ++i)
#pragma unroll
    for (int j = 0; j < 4; ++j) acc[i][j] = (f32x4)0.0f;

  const unsigned short* arow[4];
  if constexpr (AMODE == 2) {
#pragma unroll
    for (int w2 = 0; w2 < 4; ++w2) {
      const int r = mblk * 128 + w2 * 32 + grow0;
      const int bb = r / NT;
      const int pix = pixw[r];
      arow[w2] = Abf + ((size_t)bb * HWHW + pix) * 128 + gcol_swz;
    }
  }

  for (int kt = 0; kt < KSTEPS; ++kt) {
    __syncthreads();
    // ---- stage A ----
    if constexpr (AMODE == 0) {
#pragma unroll
      for (int w2 = 0; w2 < 4; ++w2) {
        const int r = w2 * 32 + grow0;
        const float* g = Af32 + (size_t)(mblk * 128 + r) * KW + kt * 64 + gcol_lin;
        const float4 f0 = *(const float4*)g;
        const float4 f1 = *(const float4*)(g + 4);
        bf16x8 v;
        v[0] = (short)f2bf(f0.x); v[1] = (short)f2bf(f0.y);
        v[2] = (short)f2bf(f0.z); v[3] = (short)f2bf(f0.w);
        v[4] = (short)f2bf(f1.x); v[5] = (short)f2bf(f1.y);
        v[6] = (short)f2bf(f1.z); v[7] = (short)f2bf(f1.w);
        *(bf16x8*)&lds[w2 * 2048 + wave * 512 + g3 * 64 + gcol_swz] = v;
      }
    } else if constexpr (AMODE == 1) {
#pragma unroll
      for (int w2 = 0; w2 < 4; ++w2) {
        const unsigned short* g =
            Abf + (size_t)(mblk * 128 + w2 * 32 + grow0) * KW + kt * 64 + gcol_swz;
        gll16(g, &lds[w2 * 2048 + wave * 512]);
      }
    } else {
#pragma unroll
      for (int w2 = 0; w2 < 4; ++w2)
        gll16(arow[w2] + kt * 64, &lds[w2 * 2048 + wave * 512]);
    }
    // ---- stage B (weights) ----
#pragma unroll
    for (int w2 = 0; w2 < 4; ++w2) {
      const unsigned short* g =
          Bw + (size_t)(nblk * 128 + w2 * 32 + grow0) * KW + kt * 64 + gcol_swz;
      gll16(g, &lds[8192 + w2 * 2048 + wave * 512]);
    }
    __syncthreads();
    // ---- MFMA ----
#pragma unroll
    for (int ks = 0; ks < 2; ++ks) {
      const int swz = ((ks * 4 + kg) ^ (l16 & 7)) * 8;
      bf16x8 a[4], b[4];
#pragma unroll
      for (int mf = 0; mf < 4; ++mf)
        a[mf] = *(const bf16x8*)&lds[(wm * 64 + mf * 16 + l16) * 64 + swz];
#pragma unroll
      for (int nf = 0; nf < 4; ++nf)
        b[nf] = *(const bf16x8*)&lds[8192 + (wn * 64 + nf * 16 + l16) * 64 + swz];
#pragma unroll
      for (int mf = 0; mf < 4; ++mf)
#pragma unroll
        for (int nf = 0; nf < 4; ++nf)
          acc[mf][nf] = __builtin_amdgcn_mfma_f32_16x16x32_bf16(a[mf], b[nf], acc[mf][nf], 0, 0, 0);
    }
  }

  // ---- epilogue ----
  if constexpr (EPI == 0) {
    float bv[4];
#pragma unroll
    for (int nf = 0; nf < 4; ++nf) {
      const int colg = nblk * 128 + wn * 64 + nf * 16 + l16;
      bv[nf] = bias ? bias[colg] : 0.0f;
    }
#pragma unroll
    for (int mf = 0; mf < 4; ++mf) {
#pragma unroll
      for (int j = 0; j < 4; ++j) {
        const int row = mblk * 128 + wm * 64 + mf * 16 + kg * 4 + j;
        unsigned short* dr = Dbf + (size_t)row * NOUT + nblk * 128 + wn * 64 + l16;
#pragma unroll
        for (int nf = 0; nf < 4; ++nf)
          dr[nf * 16] = f2bf(acc[mf][nf][j] + bv[nf]);
      }
    }
  } else if constexpr (EPI == 1) {
    // scatter + block column sums
    __syncthreads();
    float* smean = (float*)lds;  // [2][128]
    smean[tid] = 0.0f;
    __syncthreads();
    const int b0 = (mblk * 128) / NT;
#pragma unroll
    for (int mf = 0; mf < 4; ++mf) {
      const int baser = mblk * 128 + wm * 64 + mf * 16 + kg * 4;
      const int bb = baser / NT;          // uniform over j (NT % 4 == 0)
      const int bsel = (bb != b0) ? 1 : 0;
      float s[4] = {0.0f, 0.0f, 0.0f, 0.0f};
#pragma unroll
      for (int j = 0; j < 4; ++j) {
        const int row = baser + j;
        const int pix = pixw[row];
        float* dr = aux + ((size_t)bb * HWHW + pix) * 128 + wn * 64 + l16;
#pragma unroll
        for (int nf = 0; nf < 4; ++nf) {
          atomicAdd(dr + nf * 16, acc[mf][nf][j]);
          s[nf] += acc[mf][nf][j];
        }
      }
#pragma unroll
      for (int nf = 0; nf < 4; ++nf)
        atomicAdd(&smean[bsel * 128 + wn * 64 + nf * 16 + l16], s[nf]);
    }
    __syncthreads();
    const int b1 = (mblk * 128 + 127) / NT;
    if (tid < 128) atomicAdd(meanr + (size_t)b0 * 128 + tid, smean[tid]);
    else if (b1 != b0) atomicAdd(meanr + (size_t)b1 * 128 + (tid - 128), smean[tid]);
  } else {
    // EPI 2: logits. head = wn*2 + (nf>>1); reduce over l16 group.
    __syncthreads();
    float* part = (float*)lds;  // [128][4]
    float bv[4];
#pragma unroll
    for (int nf = 0; nf < 4; ++nf)
      bv[nf] = bias[wn * 64 + nf * 16 + l16];
#pragma unroll
    for (int mf = 0; mf < 4; ++mf) {
#pragma unroll
      for (int j = 0; j < 4; ++j) {
        const int rl = wm * 64 + mf * 16 + kg * 4 + j;
        const int row = mblk * 128 + rl;
        const unsigned short* kr = kvb + (size_t)row * 256 + wn * 64 + l16;
        float s0 = (acc[mf][0][j] + bv[0]) * b2f(kr[0]) +
                   (acc[mf][1][j] + bv[1]) * b2f(kr[16]);
        float s1 = (acc[mf][2][j] + bv[2]) * b2f(kr[32]) +
                   (acc[mf][3][j] + bv[3]) * b2f(kr[48]);
        s0 += __shfl_xor(s0, 8, 16); s0 += __shfl_xor(s0, 4, 16);
        s0 += __shfl_xor(s0, 2, 16); s0 += __shfl_xor(s0, 1, 16);
        s1 += __shfl_xor(s1, 8, 16); s1 += __shfl_xor(s1, 4, 16);
        s1 += __shfl_xor(s1, 2, 16); s1 += __shfl_xor(s1, 1, 16);
        if (l16 == 0) {
          part[rl * 4 + wn * 2 + 0] = s0;
          part[rl * 4 + wn * 2 + 1] = s1;
        }
      }
    }
    __syncthreads();
    if (tid < 128) {
      const int row = mblk * 128 + tid;
      const int bb = row / NT, n = row - bb * NT;
#pragma unroll
      for (int h = 0; h < 4; ++h)
        aux[((size_t)bb * NHEADS + h) * NT + n] = part[tid * 4 + h] * SCALE_C;
    }
  }
}

// ---------------------------------------------------------------------------
// k_smpart: per-(bh, chunk) partial max & sum-exp.  NT = 8 * 2500.
// ---------------------------------------------------------------------------
__global__ __launch_bounds__(256) void k_smpart(
    const float* __restrict__ logits, float* __restrict__ pm,
    float* __restrict__ ps)
{
  const int ch = blockIdx.x, bh = blockIdx.y;
  const float* L = logits + (size_t)bh * NT + ch * 2500;
  const int tid = threadIdx.x;
  __shared__ float sred[4];

  float m = -INFINITY;
  for (int i = tid; i < 2500; i += 256) m = fmaxf(m, L[i]);
  m = warpMax(m);
  if ((tid & 63) == 0) sred[tid >> 6] = m;
  __syncthreads();
  m = fmaxf(fmaxf(sred[0], sred[1]), fmaxf(sred[2], sred[3]));

  float s = 0.0f;
  for (int i = tid; i < 2500; i += 256) s += __expf(L[i] - m);
  s = warpSum(s);
  __syncthreads();
  if ((tid & 63) == 0) sred[tid >> 6] = s;
  __syncthreads();
  if (tid == 0) {
    pm[bh * 8 + ch] = m;
    ps[bh * 8 + ch] = sred[0] + sred[1] + sred[2] + sred[3];
  }
}

// ---------------------------------------------------------------------------
// k_cntfix: block b: cnt[b] = #hit pixels. Block 0 also combines softmax
// partials -> smM, smSinv.
// ---------------------------------------------------------------------------
__global__ __launch_bounds__(256) void k_cntfix(
    const float* __restrict__ hits, float* __restrict__ cnt,
    const float* __restrict__ pm, const float* __restrict__ ps,
    float* __restrict__ smM, float* __restrict__ smSinv)
{
  const int b = blockIdx.x;
  const int tid = threadIdx.x;
  float s = 0.0f;
  for (int i = tid; i < HWHW; i += 256)
    s += (hits[(size_t)b * HWHW + i] > 0.0f) ? 1.0f : 0.0f;
  s = warpSum(s);
  __shared__ float sred[4];
  if ((tid & 63) == 0) sred[tid >> 6] = s;
  __syncthreads();
  if (tid == 0) cnt[b] = sred[0] + sred[1] + sred[2] + sred[3];
  if (b == 0 && tid < BB * NHEADS) {
    float M = -INFINITY;
#pragma unroll
    for (int c = 0; c < 8; ++c) M = fmaxf(M, pm[tid * 8 + c]);
    float S = 0.0f;
#pragma unroll
    for (int c = 0; c < 8; ++c) S += ps[tid * 8 + c] * __expf(pm[tid * 8 + c] - M);
    smM[tid] = M;
    smSinv[tid] = 1.0f / S;
  }
}

// ---------------------------------------------------------------------------
// k_fused: fused_bf[ng][o] = v[ng][o] * softmax(logit)*gate
// ---------------------------------------------------------------------------
__global__ __launch_bounds__(256) void k_fused(
    const unsigned short* __restrict__ kv, const float* __restrict__ logits,
    const float* __restrict__ smM, const float* __restrict__ smSinv,
    const float* __restrict__ gate, unsigned short* __restrict__ fused)
{
  const int t = blockIdx.x * 256 + threadIdx.x;
  const int ng = t >> 3, l8 = t & 7;
  const int b = ng / NT, n = ng - b * NT;
  const int bh = b * NHEADS + (l8 >> 1);
  const float l = logits[(size_t)bh * NT + n];
  const float a = __expf(l - smM[bh]) * smSinv[bh] * gate[(size_t)b * NT + n];
  const bf16x8* vr = (const bf16x8*)(kv + (size_t)ng * 256 + 128 + l8 * 16);
  const bf16x8 v0 = vr[0], v1 = vr[1];
  bf16x8 o0, o1;
#pragma unroll
  for (int e = 0; e < 8; ++e) o0[e] = (short)f2bf(b2f((unsigned short)v0[e]) * a);
#pragma unroll
  for (int e = 0; e < 8; ++e) o1[e] = (short)f2bf(b2f((unsigned short)v1[e]) * a);
  unsigned short* dst = fused + (size_t)ng * 128 + l8 * 16;
  ((bf16x8*)dst)[0] = o0;
  ((bf16x8*)dst)[1] = o1;
}

// ---------------------------------------------------------------------------
// k_final: out[b][c][hw] = lidar + (delta[b][hw][c] - mean*mask)*alpha*gamma
// 80px x 128ch tiles; float4 global I/O; XOR-swizzled LDS (conflict-free).
// ---------------------------------------------------------------------------
__global__ __launch_bounds__(256) void k_final(
    const float* __restrict__ lidar, const float* __restrict__ alpha,
    const float* __restrict__ hits, const float* __restrict__ mean_raw,
    const float* __restrict__ cnt, const float* __restrict__ delta,
    float* __restrict__ out)
{
  __shared__ float tile[80 * 136];
  const int b = blockIdx.y;
  const int p0 = blockIdx.x * 80;
  const int t = threadIdx.x;
  const float4* dsrc = (const float4*)(delta + ((size_t)b * HWHW + p0) * 128);
#pragma unroll
  for (int i = 0; i < 10; ++i) {
    const int idx4 = i * 256 + t;         // 2560 float4 = 80px * 32
    const int p = idx4 >> 5, c4 = idx4 & 31;
    const float4 f = dsrc[idx4];
    *(float4*)&tile[p * 136 + ((c4 ^ (p & 7)) << 2)] = f;
  }
  __syncthreads();
  const int c = t >> 1, half = t & 1;
  const int cq = c >> 2, cr = c & 3;
  const float mn = mean_raw[b * 128 + c] / (cnt[b] + EPS_C);
  const size_t cbase = ((size_t)b * CC + c) * HWHW + p0;
  const size_t hbase = (size_t)b * HWHW + p0;
#pragma unroll
  for (int q = 0; q < 10; ++q) {
    const int pq = (half * 10 + q) * 4;
    float4 d;
    d.x = tile[(pq + 0) * 136 + (((cq ^ ((pq + 0) & 7)) << 2) | cr)];
    d.y = tile[(pq + 1) * 136 + (((cq ^ ((pq + 1) & 7)) << 2) | cr)];
    d.z = tile[(pq + 2) * 136 + (((cq ^ ((pq + 2) & 7)) << 2) | cr)];
    d.w = tile[(pq + 3) * 136 + (((cq ^ ((pq + 3) & 7)) << 2) | cr)];
    const float4 li = *(const float4*)(lidar + cbase + pq);
    const float4 al = *(const float4*)(alpha + p0 + pq);
    const float4 ht = *(const float4*)(hits + hbase + pq);
    float4 o;
    o.x = li.x + (d.x - (ht.x > 0.0f ? mn : 0.0f)) * al.x * GAMMA_C;
    o.y = li.y + (d.y - (ht.y > 0.0f ? mn : 0.0f)) * al.y * GAMMA_C;
    o.z = li.z + (d.z - (ht.z > 0.0f ? mn : 0.0f)) * al.z * GAMMA_C;
    o.w = li.w + (d.w - (ht.w > 0.0f ? mn : 0.0f)) * al.w * GAMMA_C;
    *(float4*)(out + cbase + pq) = o;
  }
}

// ---------------------------------------------------------------------------
extern "C" void kernel_launch(void* const* d_in, const int* in_sizes, int n_in,
                              void* d_out, int out_size, void* d_ws, size_t ws_size,
                              hipStream_t stream)
{
  const float* lidar  = (const float*)d_in[0];
  const float* tokens = (const float*)d_in[1];
  const float* gate   = (const float*)d_in[2];
  const float* alpha  = (const float*)d_in[3];
  const float* q_w    = (const float*)d_in[4];
  const float* q_b    = (const float*)d_in[5];
  const float* k_w    = (const float*)d_in[6];
  const float* v_w    = (const float*)d_in[7];
  const float* out_w  = (const float*)d_in[8];
  const int*   cidx   = (const int*)d_in[9];
  float* out = (float*)d_out;

  char* W = (char*)d_ws;
  // kv_bf [80000][256] bf16
  unsigned short* kv_bf = (unsigned short*)(W + 0);                 // 40,960,000
  // fused_bf [80000][128] bf16
  unsigned short* fused_bf = (unsigned short*)(W + 40960000);       // 20,480,000
  // delta [B][HW][128] f32 (66,355,200). Until its memset this region also
  // hosts lidar_t (at +20,480,000 within; 33,177,600) — dead before memset.
  float* delta = (float*)(W + 61440000);
  unsigned short* lidar_t = (unsigned short*)(W + 81920000);
  float* logits   = (float*)(W + 127795200);   // 1,280,000
  int*   pix_ws   = (int*)(W + 129075200);     //   320,000
  float* hits     = (float*)(W + 129395200);   //   518,400
  float* mean_raw = (float*)(W + 129913600);   //     2,048
  float* cnt      = (float*)(W + 129915648);   //        64
  unsigned short* kvw_bf = (unsigned short*)(W + 129915712);  // 131,072
  unsigned short* qw_bf  = (unsigned short*)(W + 130046784);  //  32,768
  unsigned short* ow_bf  = (unsigned short*)(W + 130079552);  //  32,768
  float* pm     = (float*)(W + 130112320);     // 512
  float* ps     = (float*)(W + 130112832);     // 512
  float* smM    = (float*)(W + 130113344);     // 64
  float* smSinv = (float*)(W + 130113408);     // 64

  hipMemsetAsync(hits, 0, (size_t)BB * HWHW * sizeof(float), stream);
  hipMemsetAsync(mean_raw, 0, 2048 + 64, stream);

  k_prep_pix<<<dim3(409), 256, 0, stream>>>(k_w, v_w, q_w, out_w, kvw_bf,
                                            qw_bf, ow_bf, cidx, pix_ws, hits);
  k_tr2<<<dim3(127, BB, 2), 256, 0, stream>>>(lidar, lidar_t);
  // kv projection: [80000,256] x [256,256]^T
  k_gemm<4, 256, 0, 0, 256><<<dim3(625, 2), 256, 0, stream>>>(
      tokens, nullptr, kvw_bf, nullptr, kv_bf, nullptr, nullptr, nullptr, nullptr);
  // q projection (rows gathered from lidar_t) -> per-head logits directly
  k_gemm<2, 128, 2, 2, 128><<<dim3(625, 1), 256, 0, stream>>>(
      nullptr, lidar_t, qw_bf, q_b, nullptr, pix_ws, logits, kv_bf, nullptr);
  // lidar_t dead from here
  hipMemsetAsync(delta, 0, (size_t)BB * HWHW * 128 * sizeof(float), stream);
  k_smpart<<<dim3(8, BB * NHEADS), 256, 0, stream>>>(logits, pm, ps);
  k_cntfix<<<dim3(BB), 256, 0, stream>>>(hits, cnt, pm, ps, smM, smSinv);
  k_fused<<<dim3(2500), 256, 0, stream>>>(kv_bf, logits, smM, smSinv, gate, fused_bf);
  // out projection + scatter + mean accumulation
  k_gemm<2, 128, 1, 1, 128><<<dim3(625, 1), 256, 0, stream>>>(
      nullptr, fused_bf, ow_bf, nullptr, nullptr, pix_ws, delta, nullptr, mean_raw);
  k_final<<<dim3(405, BB), 256, 0, stream>>>(lidar, alpha, hits, mean_raw, cnt,
                                             delta, out);
}

// Round 5
// 247.241 us; speedup vs baseline: 6.7027x; 1.0475x over previous
//
#include <hip/hip_runtime.h>

#define BB 4
#define CC 128
#define HH 180
#define WWW 180
#define HWHW (HH*WWW)       // 32400
#define CCAMD 256
#define NHEADS 4
#define HDD 128
#define NT 20000
#define MTOT 80000          // B*N, = 625 * 128 exactly
#define GAMMA_C 0.08f
#define EPS_C 1e-6f
#define SCALE_C 0.17677669529663687f  // 1/sqrt(32)

typedef short bf16x8 __attribute__((ext_vector_type(8)));
typedef float f32x4 __attribute__((ext_vector_type(4)));

typedef __attribute__((address_space(1))) const unsigned int GU;
typedef __attribute__((address_space(3))) unsigned int LU;

static __device__ __forceinline__ void gll16(const void* g, void* l) {
  __builtin_amdgcn_global_load_lds((GU*)g, (LU*)l, 16, 0, 0);
}

static __device__ __forceinline__ unsigned short f2bf(float x) {
  unsigned int b = __float_as_uint(x);
  unsigned int r = (b + 0x7fffu + ((b >> 16) & 1u)) >> 16;
  return (unsigned short)r;
}
static __device__ __forceinline__ float b2f(unsigned short u) {
  return __uint_as_float(((unsigned int)u) << 16);
}

static __device__ __forceinline__ float warpMax(float v) {
#pragma unroll
  for (int o = 32; o >= 1; o >>= 1) v = fmaxf(v, __shfl_xor(v, o));
  return v;
}
static __device__ __forceinline__ float warpSum(float v) {
#pragma unroll
  for (int o = 32; o >= 1; o >>= 1) v += __shfl_xor(v, o);
  return v;
}

// ---------------------------------------------------------------------------
// k_prep_pix: blocks 0..95: weight f32->bf16; blocks 96..408: pixel indices.
// ---------------------------------------------------------------------------
__global__ __launch_bounds__(256) void k_prep_pix(
    const float* __restrict__ kw, const float* __restrict__ vw,
    const float* __restrict__ qw, const float* __restrict__ ow,
    unsigned short* __restrict__ kvw, unsigned short* __restrict__ qwb,
    unsigned short* __restrict__ owb, const int* __restrict__ cidx,
    int* __restrict__ pix_ws, float* __restrict__ hits)
{
  if (blockIdx.x < 96) {
    const int t = blockIdx.x * 256 + threadIdx.x;  // one float4 per thread
    float4 f;
    unsigned short* dst;
    if (t < 16384) {           // kv: 65536 elems
      f = (t < 8192) ? ((const float4*)kw)[t] : ((const float4*)vw)[t - 8192];
      dst = kvw + (size_t)t * 4;
    } else if (t < 20480) {    // q: 16384 elems
      const int i = t - 16384;
      f = ((const float4*)qw)[i];
      dst = qwb + (size_t)i * 4;
    } else {                   // out: 16384 elems
      const int i = t - 20480;
      f = ((const float4*)ow)[i];
      dst = owb + (size_t)i * 4;
    }
    ushort4 u;
    u.x = f2bf(f.x); u.y = f2bf(f.y); u.z = f2bf(f.z); u.w = f2bf(f.w);
    *(ushort4*)dst = u;
  } else {
    const int t = (blockIdx.x - 96) * 256 + threadIdx.x;
    if (t >= MTOT) return;
    const int2 ij = *(const int2*)(cidx + (size_t)t * 2);
    int ii = ij.x; ii = ii < 0 ? 0 : (ii > HH - 1 ? HH - 1 : ii);
    int jj = ij.y; jj = jj < 0 ? 0 : (jj > WWW - 1 ? WWW - 1 : jj);
    const int pix = ii * WWW + jj;
    pix_ws[t] = pix;
    atomicAdd(hits + (size_t)(t / NT) * HWHW + pix, 1.0f);
  }
}

// ---------------------------------------------------------------------------
// k_tr2: lidar_t[b][p][c] (bf16) = lidar[b][c][p].
// ---------------------------------------------------------------------------
__global__ __launch_bounds__(256) void k_tr2(
    const float* __restrict__ lidar, unsigned short* __restrict__ lidar_t)
{
  const int b = blockIdx.y;
  const int p = blockIdx.x * 256 + threadIdx.x;
  if (p >= HWHW) return;
  const int z = blockIdx.z;  // channel half
  const float* src = lidar + ((size_t)b * CC + z * 64) * HWHW + p;
  unsigned short* dst = lidar_t + ((size_t)b * HWHW + p) * 128 + z * 64;
#pragma unroll
  for (int c8 = 0; c8 < 8; ++c8) {
    bf16x8 v;
#pragma unroll
    for (int e = 0; e < 8; ++e)
      v[e] = (short)f2bf(src[(size_t)(c8 * 8 + e) * HWHW]);
    ((bf16x8*)dst)[c8] = v;
  }
}

// ---------------------------------------------------------------------------
// k_gemm: C[M=80000, NOUT] = A[M,K] * W[NOUT,K]^T   (bf16 MFMA 16x16x32)
// BM=BN=128, BK=64, 4 waves 2x2, each wave 64x64 (4x4 fragments).
// AMODE 0: A f32 reg-staged+cvt. AMODE 1: A bf16 rows via gll16.
// AMODE 2: A bf16 rows gathered from lidar_t via pixw.
// AMODE 3: A = V-half of kvb multiplied on-the-fly by softmax(logit)*gate
//          (fused attention-weighted V; reg-staged).
// LDS XOR-swizzled on the source side; matching swizzle on ds_read.
// EPI 0: store bf16 rows (+opt bias).
// EPI 1: atomic f32 scatter into delta[B][HW][128] at pixw[row], plus
//        block-level column sums -> atomicAdd into meanr[b][c].
// EPI 2: per-head logits: logit[b,h,n] = SCALE * sum_d (acc+bias)*k  (k=kvb).
// ---------------------------------------------------------------------------
template<int KSTEPS, int KW, int AMODE, int EPI, int NOUT>
__global__ __launch_bounds__(256) void k_gemm(
    const float* __restrict__ Af32, const unsigned short* __restrict__ Abf,
    const unsigned short* __restrict__ Bw, const float* __restrict__ bias,
    unsigned short* __restrict__ Dbf, const int* __restrict__ pixw,
    float* __restrict__ aux,            // EPI1: delta; EPI2: logits out
    const unsigned short* __restrict__ kvb, float* __restrict__ meanr,
    const float* __restrict__ smMp, const float* __restrict__ smSinvp,
    const float* __restrict__ gatep, const float* __restrict__ logp)
{
  __shared__ unsigned short lds[16384];  // A: [0,8192), B: [8192,16384)
  const int tid = threadIdx.x;
  const int lane = tid & 63, wave = tid >> 6;
  const int wm = wave >> 1, wn = wave & 1;
  const int mblk = blockIdx.x, nblk = blockIdx.y;
  const int l16 = lane & 15, kg = lane >> 4;

  const int g3 = lane >> 3;        // row within 8-row group (== lds_row & 7)
  const int c8l = lane & 7;
  const int grow0 = wave * 8 + g3;
  const int gcol_lin = c8l * 8;
  const int gcol_swz = (c8l ^ g3) * 8;

  f32x4 acc[4][4];
#pragma unroll
  for (int i = 0; i < 4; ++i)
#pragma unroll
    for (int j = 0; j < 4; ++j) acc[i][j] = (f32x4)0.0f;

  const unsigned short* arow[4];
  if constexpr (AMODE == 2) {
#pragma unroll
    for (int w2 = 0; w2 < 4; ++w2) {
      const int r = mblk * 128 + w2 * 32 + grow0;
      const int bb = r / NT;
      const int pix = pixw[r];
      arow[w2] = Abf + ((size_t)bb * HWHW + pix) * 128 + gcol_swz;
    }
  }

  const unsigned short* vrow[4];
  float ga4[4];
  int lbase[4], rb4[4];
  if constexpr (AMODE == 3) {
#pragma unroll
    for (int w2 = 0; w2 < 4; ++w2) {
      const int r = mblk * 128 + w2 * 32 + grow0;
      const int bb = r / NT, n = r - bb * NT;
      vrow[w2] = kvb + (size_t)r * 256 + 128 + gcol_lin;
      ga4[w2] = gatep[(size_t)bb * NT + n];
      lbase[w2] = bb * NHEADS * NT + n;
      rb4[w2] = bb;
    }
  }

  for (int kt = 0; kt < KSTEPS; ++kt) {
    __syncthreads();
    // ---- stage A ----
    if constexpr (AMODE == 0) {
#pragma unroll
      for (int w2 = 0; w2 < 4; ++w2) {
        const int r = w2 * 32 + grow0;
        const float* g = Af32 + (size_t)(mblk * 128 + r) * KW + kt * 64 + gcol_lin;
        const float4 f0 = *(const float4*)g;
        const float4 f1 = *(const float4*)(g + 4);
        bf16x8 v;
        v[0] = (short)f2bf(f0.x); v[1] = (short)f2bf(f0.y);
        v[2] = (short)f2bf(f0.z); v[3] = (short)f2bf(f0.w);
        v[4] = (short)f2bf(f1.x); v[5] = (short)f2bf(f1.y);
        v[6] = (short)f2bf(f1.z); v[7] = (short)f2bf(f1.w);
        *(bf16x8*)&lds[w2 * 2048 + wave * 512 + g3 * 64 + gcol_swz] = v;
      }
    } else if constexpr (AMODE == 1) {
#pragma unroll
      for (int w2 = 0; w2 < 4; ++w2) {
        const unsigned short* g =
            Abf + (size_t)(mblk * 128 + w2 * 32 + grow0) * KW + kt * 64 + gcol_swz;
        gll16(g, &lds[w2 * 2048 + wave * 512]);
      }
    } else if constexpr (AMODE == 2) {
#pragma unroll
      for (int w2 = 0; w2 < 4; ++w2)
        gll16(arow[w2] + kt * 64, &lds[w2 * 2048 + wave * 512]);
    } else {
      // AMODE 3: fused = v * softmax(logit)*gate, reg-staged
      const int h = kt * 2 + (c8l >> 2);
#pragma unroll
      for (int w2 = 0; w2 < 4; ++w2) {
        const int bh = rb4[w2] * NHEADS + h;
        const float a =
            __expf(logp[lbase[w2] + h * NT] - smMp[bh]) * smSinvp[bh] * ga4[w2];
        const bf16x8 v = *(const bf16x8*)(vrow[w2] + kt * 64);
        bf16x8 o;
#pragma unroll
        for (int e = 0; e < 8; ++e)
          o[e] = (short)f2bf(b2f((unsigned short)v[e]) * a);
        *(bf16x8*)&lds[w2 * 2048 + wave * 512 + g3 * 64 + gcol_swz] = o;
      }
    }
    // ---- stage B (weights) ----
#pragma unroll
    for (int w2 = 0; w2 < 4; ++w2) {
      const unsigned short* g =
          Bw + (size_t)(nblk * 128 + w2 * 32 + grow0) * KW + kt * 64 + gcol_swz;
      gll16(g, &lds[8192 + w2 * 2048 + wave * 512]);
    }
    __syncthreads();
    // ---- MFMA ----
#pragma unroll
    for (int ks = 0; ks < 2; ++ks) {
      const int swz = ((ks * 4 + kg) ^ (l16 & 7)) * 8;
      bf16x8 a[4], b[4];
#pragma unroll
      for (int mf = 0; mf < 4; ++mf)
        a[mf] = *(const bf16x8*)&lds[(wm * 64 + mf * 16 + l16) * 64 + swz];
#pragma unroll
      for (int nf = 0; nf < 4; ++nf)
        b[nf] = *(const bf16x8*)&lds[8192 + (wn * 64 + nf * 16 + l16) * 64 + swz];
#pragma unroll
      for (int mf = 0; mf < 4; ++mf)
#pragma unroll
        for (int nf = 0; nf < 4; ++nf)
          acc[mf][nf] = __builtin_amdgcn_mfma_f32_16x16x32_bf16(a[mf], b[nf], acc[mf][nf], 0, 0, 0);
    }
  }

  // ---- epilogue ----
  if constexpr (EPI == 0) {
    float bv[4];
#pragma unroll
    for (int nf = 0; nf < 4; ++nf) {
      const int colg = nblk * 128 + wn * 64 + nf * 16 + l16;
      bv[nf] = bias ? bias[colg] : 0.0f;
    }
#pragma unroll
    for (int mf = 0; mf < 4; ++mf) {
#pragma unroll
      for (int j = 0; j < 4; ++j) {
        const int row = mblk * 128 + wm * 64 + mf * 16 + kg * 4 + j;
        unsigned short* dr = Dbf + (size_t)row * NOUT + nblk * 128 + wn * 64 + l16;
#pragma unroll
        for (int nf = 0; nf < 4; ++nf)
          dr[nf * 16] = f2bf(acc[mf][nf][j] + bv[nf]);
      }
    }
  } else if constexpr (EPI == 1) {
    // scatter + block column sums
    __syncthreads();
    float* smean = (float*)lds;  // [2][128]
    smean[tid] = 0.0f;
    __syncthreads();
    const int b0 = (mblk * 128) / NT;
#pragma unroll
    for (int mf = 0; mf < 4; ++mf) {
      const int baser = mblk * 128 + wm * 64 + mf * 16 + kg * 4;
      const int bb = baser / NT;          // uniform over j (NT % 4 == 0)
      const int bsel = (bb != b0) ? 1 : 0;
      float s[4] = {0.0f, 0.0f, 0.0f, 0.0f};
#pragma unroll
      for (int j = 0; j < 4; ++j) {
        const int row = baser + j;
        const int pix = pixw[row];
        float* dr = aux + ((size_t)bb * HWHW + pix) * 128 + wn * 64 + l16;
#pragma unroll
        for (int nf = 0; nf < 4; ++nf) {
          atomicAdd(dr + nf * 16, acc[mf][nf][j]);
          s[nf] += acc[mf][nf][j];
        }
      }
#pragma unroll
      for (int nf = 0; nf < 4; ++nf)
        atomicAdd(&smean[bsel * 128 + wn * 64 + nf * 16 + l16], s[nf]);
    }
    __syncthreads();
    const int b1 = (mblk * 128 + 127) / NT;
    if (tid < 128) atomicAdd(meanr + (size_t)b0 * 128 + tid, smean[tid]);
    else if (b1 != b0) atomicAdd(meanr + (size_t)b1 * 128 + (tid - 128), smean[tid]);
  } else {
    // EPI 2: logits. head = wn*2 + (nf>>1); reduce over l16 group.
    __syncthreads();
    float* part = (float*)lds;  // [128][4]
    float bv[4];
#pragma unroll
    for (int nf = 0; nf < 4; ++nf)
      bv[nf] = bias[wn * 64 + nf * 16 + l16];
#pragma unroll
    for (int mf = 0; mf < 4; ++mf) {
#pragma unroll
      for (int j = 0; j < 4; ++j) {
        const int rl = wm * 64 + mf * 16 + kg * 4 + j;
        const int row = mblk * 128 + rl;
        const unsigned short* kr = kvb + (size_t)row * 256 + wn * 64 + l16;
        float s0 = (acc[mf][0][j] + bv[0]) * b2f(kr[0]) +
                   (acc[mf][1][j] + bv[1]) * b2f(kr[16]);
        float s1 = (acc[mf][2][j] + bv[2]) * b2f(kr[32]) +
                   (acc[mf][3][j] + bv[3]) * b2f(kr[48]);
        s0 += __shfl_xor(s0, 8, 16); s0 += __shfl_xor(s0, 4, 16);
        s0 += __shfl_xor(s0, 2, 16); s0 += __shfl_xor(s0, 1, 16);
        s1 += __shfl_xor(s1, 8, 16); s1 += __shfl_xor(s1, 4, 16);
        s1 += __shfl_xor(s1, 2, 16); s1 += __shfl_xor(s1, 1, 16);
        if (l16 == 0) {
          part[rl * 4 + wn * 2 + 0] = s0;
          part[rl * 4 + wn * 2 + 1] = s1;
        }
      }
    }
    __syncthreads();
    if (tid < 128) {
      const int row = mblk * 128 + tid;
      const int bb = row / NT, n = row - bb * NT;
#pragma unroll
      for (int h = 0; h < 4; ++h)
        aux[((size_t)bb * NHEADS + h) * NT + n] = part[tid * 4 + h] * SCALE_C;
    }
  }
}

// ---------------------------------------------------------------------------
// k_smpart: per-(bh, chunk) partial max & sum-exp.  NT = 8 * 2500.
// ---------------------------------------------------------------------------
__global__ __launch_bounds__(256) void k_smpart(
    const float* __restrict__ logits, float* __restrict__ pm,
    float* __restrict__ ps)
{
  const int ch = blockIdx.x, bh = blockIdx.y;
  const float* L = logits + (size_t)bh * NT + ch * 2500;
  const int tid = threadIdx.x;
  __shared__ float sred[4];

  float m = -INFINITY;
  for (int i = tid; i < 2500; i += 256) m = fmaxf(m, L[i]);
  m = warpMax(m);
  if ((tid & 63) == 0) sred[tid >> 6] = m;
  __syncthreads();
  m = fmaxf(fmaxf(sred[0], sred[1]), fmaxf(sred[2], sred[3]));

  float s = 0.0f;
  for (int i = tid; i < 2500; i += 256) s += __expf(L[i] - m);
  s = warpSum(s);
  __syncthreads();
  if ((tid & 63) == 0) sred[tid >> 6] = s;
  __syncthreads();
  if (tid == 0) {
    pm[bh * 8 + ch] = m;
    ps[bh * 8 + ch] = sred[0] + sred[1] + sred[2] + sred[3];
  }
}

// ---------------------------------------------------------------------------
// k_cntfix: block b: cnt[b] = #hit pixels. Block 0 also combines softmax
// partials -> smM, smSinv.
// ---------------------------------------------------------------------------
__global__ __launch_bounds__(256) void k_cntfix(
    const float* __restrict__ hits, float* __restrict__ cnt,
    const float* __restrict__ pm, const float* __restrict__ ps,
    float* __restrict__ smM, float* __restrict__ smSinv)
{
  const int b = blockIdx.x;
  const int tid = threadIdx.x;
  float s = 0.0f;
  for (int i = tid; i < HWHW; i += 256)
    s += (hits[(size_t)b * HWHW + i] > 0.0f) ? 1.0f : 0.0f;
  s = warpSum(s);
  __shared__ float sred[4];
  if ((tid & 63) == 0) sred[tid >> 6] = s;
  __syncthreads();
  if (tid == 0) cnt[b] = sred[0] + sred[1] + sred[2] + sred[3];
  if (b == 0 && tid < BB * NHEADS) {
    float M = -INFINITY;
#pragma unroll
    for (int c = 0; c < 8; ++c) M = fmaxf(M, pm[tid * 8 + c]);
    float S = 0.0f;
#pragma unroll
    for (int c = 0; c < 8; ++c) S += ps[tid * 8 + c] * __expf(pm[tid * 8 + c] - M);
    smM[tid] = M;
    smSinv[tid] = 1.0f / S;
  }
}

// ---------------------------------------------------------------------------
// k_final: out[b][c][hw] = lidar + (delta[b][hw][c] - mean*mask)*alpha*gamma
// 40px x 128ch tiles (LDS 21.8KB -> 7 blocks/CU); hits-gated delta reads;
// float4 global I/O; XOR-swizzled LDS.
// ---------------------------------------------------------------------------
__global__ __launch_bounds__(256) void k_final(
    const float* __restrict__ lidar, const float* __restrict__ alpha,
    const float* __restrict__ hits, const float* __restrict__ mean_raw,
    const float* __restrict__ cnt, const float* __restrict__ delta,
    float* __restrict__ out)
{
  __shared__ float tile[40 * 136];
  const int b = blockIdx.y;
  const int p0 = blockIdx.x * 40;
  const int t = threadIdx.x;
  const float4* dsrc = (const float4*)(delta + ((size_t)b * HWHW + p0) * 128);
  const float* hrow = hits + (size_t)b * HWHW + p0;
#pragma unroll
  for (int i = 0; i < 5; ++i) {
    const int idx4 = i * 256 + t;         // 1280 float4 = 40px * 32
    const int p = idx4 >> 5, c4 = idx4 & 31;
    float4 f = make_float4(0.0f, 0.0f, 0.0f, 0.0f);
    if (hrow[p] > 0.0f) f = dsrc[idx4];
    *(float4*)&tile[p * 136 + ((c4 ^ (p & 7)) << 2)] = f;
  }
  __syncthreads();
  const int c = t >> 1, half = t & 1;
  const int cq = c >> 2, cr = c & 3;
  const float mn = mean_raw[b * 128 + c] / (cnt[b] + EPS_C);
  const size_t cbase = ((size_t)b * CC + c) * HWHW + p0;
  const size_t hbase = (size_t)b * HWHW + p0;
#pragma unroll
  for (int q = 0; q < 5; ++q) {
    const int pq = (half * 5 + q) * 4;
    float4 d;
    d.x = tile[(pq + 0) * 136 + (((cq ^ ((pq + 0) & 7)) << 2) | cr)];
    d.y = tile[(pq + 1) * 136 + (((cq ^ ((pq + 1) & 7)) << 2) | cr)];
    d.z = tile[(pq + 2) * 136 + (((cq ^ ((pq + 2) & 7)) << 2) | cr)];
    d.w = tile[(pq + 3) * 136 + (((cq ^ ((pq + 3) & 7)) << 2) | cr)];
    const float4 li = *(const float4*)(lidar + cbase + pq);
    const float4 al = *(const float4*)(alpha + p0 + pq);
    const float4 ht = *(const float4*)(hits + hbase + pq);
    float4 o;
    o.x = li.x + (d.x - (ht.x > 0.0f ? mn : 0.0f)) * al.x * GAMMA_C;
    o.y = li.y + (d.y - (ht.y > 0.0f ? mn : 0.0f)) * al.y * GAMMA_C;
    o.z = li.z + (d.z - (ht.z > 0.0f ? mn : 0.0f)) * al.z * GAMMA_C;
    o.w = li.w + (d.w - (ht.w > 0.0f ? mn : 0.0f)) * al.w * GAMMA_C;
    *(float4*)(out + cbase + pq) = o;
  }
}

// ---------------------------------------------------------------------------
extern "C" void kernel_launch(void* const* d_in, const int* in_sizes, int n_in,
                              void* d_out, int out_size, void* d_ws, size_t ws_size,
                              hipStream_t stream)
{
  const float* lidar  = (const float*)d_in[0];
  const float* tokens = (const float*)d_in[1];
  const float* gate   = (const float*)d_in[2];
  const float* alpha  = (const float*)d_in[3];
  const float* q_w    = (const float*)d_in[4];
  const float* q_b    = (const float*)d_in[5];
  const float* k_w    = (const float*)d_in[6];
  const float* v_w    = (const float*)d_in[7];
  const float* out_w  = (const float*)d_in[8];
  const int*   cidx   = (const int*)d_in[9];
  float* out = (float*)d_out;

  char* W = (char*)d_ws;
  // kv_bf [80000][256] bf16
  unsigned short* kv_bf = (unsigned short*)(W + 0);                 // 40,960,000
  // delta [B][HW][128] f32 (66,355,200). Until its memset this region also
  // hosts lidar_t (at +20,480,000 within; 33,177,600) — dead before memset.
  float* delta = (float*)(W + 61440000);
  unsigned short* lidar_t = (unsigned short*)(W + 81920000);
  float* logits   = (float*)(W + 127795200);   // 1,280,000
  int*   pix_ws   = (int*)(W + 129075200);     //   320,000
  float* hits     = (float*)(W + 129395200);   //   518,400
  float* mean_raw = (float*)(W + 129913600);   //     2,048
  float* cnt      = (float*)(W + 129915648);   //        64
  unsigned short* kvw_bf = (unsigned short*)(W + 129915712);  // 131,072
  unsigned short* qw_bf  = (unsigned short*)(W + 130046784);  //  32,768
  unsigned short* ow_bf  = (unsigned short*)(W + 130079552);  //  32,768
  float* pm     = (float*)(W + 130112320);     // 512
  float* ps     = (float*)(W + 130112832);     // 512
  float* smM    = (float*)(W + 130113344);     // 64
  float* smSinv = (float*)(W + 130113408);     // 64

  hipMemsetAsync(hits, 0, (size_t)BB * HWHW * sizeof(float), stream);
  hipMemsetAsync(mean_raw, 0, 2048 + 64, stream);

  k_prep_pix<<<dim3(409), 256, 0, stream>>>(k_w, v_w, q_w, out_w, kvw_bf,
                                            qw_bf, ow_bf, cidx, pix_ws, hits);
  k_tr2<<<dim3(127, BB, 2), 256, 0, stream>>>(lidar, lidar_t);
  // kv projection: [80000,256] x [256,256]^T
  k_gemm<4, 256, 0, 0, 256><<<dim3(625, 2), 256, 0, stream>>>(
      tokens, nullptr, kvw_bf, nullptr, kv_bf, nullptr, nullptr, nullptr,
      nullptr, nullptr, nullptr, nullptr, nullptr);
  // q projection (rows gathered from lidar_t) -> per-head logits directly
  k_gemm<2, 128, 2, 2, 128><<<dim3(625, 1), 256, 0, stream>>>(
      nullptr, lidar_t, qw_bf, q_b, nullptr, pix_ws, logits, kv_bf,
      nullptr, nullptr, nullptr, nullptr, nullptr);
  // lidar_t dead from here
  hipMemsetAsync(delta, 0, (size_t)BB * HWHW * 128 * sizeof(float), stream);
  k_smpart<<<dim3(8, BB * NHEADS), 256, 0, stream>>>(logits, pm, ps);
  k_cntfix<<<dim3(BB), 256, 0, stream>>>(hits, cnt, pm, ps, smM, smSinv);
  // out projection with fused attention-weighted V + scatter + mean accum
  k_gemm<2, 128, 3, 1, 128><<<dim3(625, 1), 256, 0, stream>>>(
      nullptr, nullptr, ow_bf, nullptr, nullptr, pix_ws, delta, kv_bf,
      mean_raw, smM, smSinv, gate, logits);
  k_final<<<dim3(810, BB), 256, 0, stream>>>(lidar, alpha, hits, mean_raw, cnt,
                                             delta, out);
}

// Round 6
// 225.272 us; speedup vs baseline: 7.3563x; 1.0975x over previous
//
#include <hip/hip_runtime.h>

#define BB 4
#define CC 128
#define HH 180
#define WWW 180
#define HWHW (HH*WWW)       // 32400
#define CCAMD 256
#define NHEADS 4
#define HDD 128
#define NT 20000
#define MTOT 80000          // B*N, = 625 * 128 exactly
#define GAMMA_C 0.08f
#define EPS_C 1e-6f
#define SCALE_C 0.17677669529663687f  // 1/sqrt(32)

typedef short bf16x8 __attribute__((ext_vector_type(8)));
typedef float f32x4 __attribute__((ext_vector_type(4)));

typedef __attribute__((address_space(1))) const unsigned int GU;
typedef __attribute__((address_space(3))) unsigned int LU;

static __device__ __forceinline__ void gll16(const void* g, void* l) {
  __builtin_amdgcn_global_load_lds((GU*)g, (LU*)l, 16, 0, 0);
}

static __device__ __forceinline__ unsigned short f2bf(float x) {
  unsigned int b = __float_as_uint(x);
  unsigned int r = (b + 0x7fffu + ((b >> 16) & 1u)) >> 16;
  return (unsigned short)r;
}
static __device__ __forceinline__ float b2f(unsigned short u) {
  return __uint_as_float(((unsigned int)u) << 16);
}

static __device__ __forceinline__ float warpMax(float v) {
#pragma unroll
  for (int o = 32; o >= 1; o >>= 1) v = fmaxf(v, __shfl_xor(v, o));
  return v;
}
static __device__ __forceinline__ float warpSum(float v) {
#pragma unroll
  for (int o = 32; o >= 1; o >>= 1) v += __shfl_xor(v, o);
  return v;
}

// ---------------------------------------------------------------------------
// k_prep_pix: blocks 0..95: weight f32->bf16; blocks 96..408: pixel indices.
// ---------------------------------------------------------------------------
__global__ __launch_bounds__(256) void k_prep_pix(
    const float* __restrict__ kw, const float* __restrict__ vw,
    const float* __restrict__ qw, const float* __restrict__ ow,
    unsigned short* __restrict__ kvw, unsigned short* __restrict__ qwb,
    unsigned short* __restrict__ owb, const int* __restrict__ cidx,
    int* __restrict__ pix_ws, float* __restrict__ hits)
{
  if (blockIdx.x < 96) {
    const int t = blockIdx.x * 256 + threadIdx.x;  // one float4 per thread
    float4 f;
    unsigned short* dst;
    if (t < 16384) {           // kv: 65536 elems
      f = (t < 8192) ? ((const float4*)kw)[t] : ((const float4*)vw)[t - 8192];
      dst = kvw + (size_t)t * 4;
    } else if (t < 20480) {    // q: 16384 elems
      const int i = t - 16384;
      f = ((const float4*)qw)[i];
      dst = qwb + (size_t)i * 4;
    } else {                   // out: 16384 elems
      const int i = t - 20480;
      f = ((const float4*)ow)[i];
      dst = owb + (size_t)i * 4;
    }
    ushort4 u;
    u.x = f2bf(f.x); u.y = f2bf(f.y); u.z = f2bf(f.z); u.w = f2bf(f.w);
    *(ushort4*)dst = u;
  } else {
    const int t = (blockIdx.x - 96) * 256 + threadIdx.x;
    if (t >= MTOT) return;
    const int2 ij = *(const int2*)(cidx + (size_t)t * 2);
    int ii = ij.x; ii = ii < 0 ? 0 : (ii > HH - 1 ? HH - 1 : ii);
    int jj = ij.y; jj = jj < 0 ? 0 : (jj > WWW - 1 ? WWW - 1 : jj);
    const int pix = ii * WWW + jj;
    pix_ws[t] = pix;
    atomicAdd(hits + (size_t)(t / NT) * HWHW + pix, 1.0f);
  }
}

// ---------------------------------------------------------------------------
// k_tr2: lidar_t[b][p][c] (bf16) = lidar[b][c][p].
// ---------------------------------------------------------------------------
__global__ __launch_bounds__(256) void k_tr2(
    const float* __restrict__ lidar, unsigned short* __restrict__ lidar_t)
{
  const int b = blockIdx.y;
  const int p = blockIdx.x * 256 + threadIdx.x;
  if (p >= HWHW) return;
  const int z = blockIdx.z;  // channel half
  const float* src = lidar + ((size_t)b * CC + z * 64) * HWHW + p;
  unsigned short* dst = lidar_t + ((size_t)b * HWHW + p) * 128 + z * 64;
#pragma unroll
  for (int c8 = 0; c8 < 8; ++c8) {
    bf16x8 v;
#pragma unroll
    for (int e = 0; e < 8; ++e)
      v[e] = (short)f2bf(src[(size_t)(c8 * 8 + e) * HWHW]);
    ((bf16x8*)dst)[c8] = v;
  }
}

// ---------------------------------------------------------------------------
// k_gemm: C[M=80000, NOUT] = A[M,K] * W[NOUT,K]^T   (bf16 MFMA 16x16x32)
// BM=BN=128, BK=64, 4 waves 2x2, each wave 64x64 (4x4 fragments).
// AMODE 0: A f32 reg-staged+cvt. AMODE 1: A bf16 rows via gll16.
// AMODE 2: A bf16 rows gathered from lidar_t via pixw.
// AMODE 3: A = V-half of kvb multiplied on-the-fly by softmax(logit)*gate
//          (fused attention-weighted V; reg-staged).
// LDS XOR-swizzled on the source side; matching swizzle on ds_read.
// EPI 0: store bf16 rows (+opt bias).
// EPI 1: atomic f32 scatter into delta[B][HW][128] at pixw[row], plus
//        block-level column sums -> atomicAdd into meanr[b][c].
// EPI 2: per-head logits: logit[b,h,n] = SCALE * sum_d (acc+bias)*k  (k=kvb).
// ---------------------------------------------------------------------------
template<int KSTEPS, int KW, int AMODE, int EPI, int NOUT>
__global__ __launch_bounds__(256) void k_gemm(
    const float* __restrict__ Af32, const unsigned short* __restrict__ Abf,
    const unsigned short* __restrict__ Bw, const float* __restrict__ bias,
    unsigned short* __restrict__ Dbf, const int* __restrict__ pixw,
    float* __restrict__ aux,            // EPI1: delta; EPI2: logits out
    const unsigned short* __restrict__ kvb, float* __restrict__ meanr,
    const float* __restrict__ smMp, const float* __restrict__ smSinvp,
    const float* __restrict__ gatep, const float* __restrict__ logp)
{
  __shared__ unsigned short lds[16384];  // A: [0,8192), B: [8192,16384)
  const int tid = threadIdx.x;
  const int lane = tid & 63, wave = tid >> 6;
  const int wm = wave >> 1, wn = wave & 1;
  const int mblk = blockIdx.x, nblk = blockIdx.y;
  const int l16 = lane & 15, kg = lane >> 4;

  const int g3 = lane >> 3;        // row within 8-row group (== lds_row & 7)
  const int c8l = lane & 7;
  const int grow0 = wave * 8 + g3;
  const int gcol_lin = c8l * 8;
  const int gcol_swz = (c8l ^ g3) * 8;

  f32x4 acc[4][4];
#pragma unroll
  for (int i = 0; i < 4; ++i)
#pragma unroll
    for (int j = 0; j < 4; ++j) acc[i][j] = (f32x4)0.0f;

  const unsigned short* arow[4];
  if constexpr (AMODE == 2) {
#pragma unroll
    for (int w2 = 0; w2 < 4; ++w2) {
      const int r = mblk * 128 + w2 * 32 + grow0;
      const int bb = r / NT;
      const int pix = pixw[r];
      arow[w2] = Abf + ((size_t)bb * HWHW + pix) * 128 + gcol_swz;
    }
  }

  const unsigned short* vrow[4];
  float ga4[4];
  int lbase[4], rb4[4];
  if constexpr (AMODE == 3) {
#pragma unroll
    for (int w2 = 0; w2 < 4; ++w2) {
      const int r = mblk * 128 + w2 * 32 + grow0;
      const int bb = r / NT, n = r - bb * NT;
      vrow[w2] = kvb + (size_t)r * 256 + 128 + gcol_lin;
      ga4[w2] = gatep[(size_t)bb * NT + n];
      lbase[w2] = bb * NHEADS * NT + n;
      rb4[w2] = bb;
    }
  }

  for (int kt = 0; kt < KSTEPS; ++kt) {
    __syncthreads();
    // ---- stage A ----
    if constexpr (AMODE == 0) {
#pragma unroll
      for (int w2 = 0; w2 < 4; ++w2) {
        const int r = w2 * 32 + grow0;
        const float* g = Af32 + (size_t)(mblk * 128 + r) * KW + kt * 64 + gcol_lin;
        const float4 f0 = *(const float4*)g;
        const float4 f1 = *(const float4*)(g + 4);
        bf16x8 v;
        v[0] = (short)f2bf(f0.x); v[1] = (short)f2bf(f0.y);
        v[2] = (short)f2bf(f0.z); v[3] = (short)f2bf(f0.w);
        v[4] = (short)f2bf(f1.x); v[5] = (short)f2bf(f1.y);
        v[6] = (short)f2bf(f1.z); v[7] = (short)f2bf(f1.w);
        *(bf16x8*)&lds[w2 * 2048 + wave * 512 + g3 * 64 + gcol_swz] = v;
      }
    } else if constexpr (AMODE == 1) {
#pragma unroll
      for (int w2 = 0; w2 < 4; ++w2) {
        const unsigned short* g =
            Abf + (size_t)(mblk * 128 + w2 * 32 + grow0) * KW + kt * 64 + gcol_swz;
        gll16(g, &lds[w2 * 2048 + wave * 512]);
      }
    } else if constexpr (AMODE == 2) {
#pragma unroll
      for (int w2 = 0; w2 < 4; ++w2)
        gll16(arow[w2] + kt * 64, &lds[w2 * 2048 + wave * 512]);
    } else {
      // AMODE 3: fused = v * softmax(logit)*gate, reg-staged
      const int h = kt * 2 + (c8l >> 2);
#pragma unroll
      for (int w2 = 0; w2 < 4; ++w2) {
        const int bh = rb4[w2] * NHEADS + h;
        const float a =
            __expf(logp[lbase[w2] + h * NT] - smMp[bh]) * smSinvp[bh] * ga4[w2];
        const bf16x8 v = *(const bf16x8*)(vrow[w2] + kt * 64);
        bf16x8 o;
#pragma unroll
        for (int e = 0; e < 8; ++e)
          o[e] = (short)f2bf(b2f((unsigned short)v[e]) * a);
        *(bf16x8*)&lds[w2 * 2048 + wave * 512 + g3 * 64 + gcol_swz] = o;
      }
    }
    // ---- stage B (weights) ----
#pragma unroll
    for (int w2 = 0; w2 < 4; ++w2) {
      const unsigned short* g =
          Bw + (size_t)(nblk * 128 + w2 * 32 + grow0) * KW + kt * 64 + gcol_swz;
      gll16(g, &lds[8192 + w2 * 2048 + wave * 512]);
    }
    __syncthreads();
    // ---- MFMA ----
#pragma unroll
    for (int ks = 0; ks < 2; ++ks) {
      const int swz = ((ks * 4 + kg) ^ (l16 & 7)) * 8;
      bf16x8 a[4], b[4];
#pragma unroll
      for (int mf = 0; mf < 4; ++mf)
        a[mf] = *(const bf16x8*)&lds[(wm * 64 + mf * 16 + l16) * 64 + swz];
#pragma unroll
      for (int nf = 0; nf < 4; ++nf)
        b[nf] = *(const bf16x8*)&lds[8192 + (wn * 64 + nf * 16 + l16) * 64 + swz];
#pragma unroll
      for (int mf = 0; mf < 4; ++mf)
#pragma unroll
        for (int nf = 0; nf < 4; ++nf)
          acc[mf][nf] = __builtin_amdgcn_mfma_f32_16x16x32_bf16(a[mf], b[nf], acc[mf][nf], 0, 0, 0);
    }
  }

  // ---- epilogue ----
  if constexpr (EPI == 0) {
    float bv[4];
#pragma unroll
    for (int nf = 0; nf < 4; ++nf) {
      const int colg = nblk * 128 + wn * 64 + nf * 16 + l16;
      bv[nf] = bias ? bias[colg] : 0.0f;
    }
#pragma unroll
    for (int mf = 0; mf < 4; ++mf) {
#pragma unroll
      for (int j = 0; j < 4; ++j) {
        const int row = mblk * 128 + wm * 64 + mf * 16 + kg * 4 + j;
        unsigned short* dr = Dbf + (size_t)row * NOUT + nblk * 128 + wn * 64 + l16;
#pragma unroll
        for (int nf = 0; nf < 4; ++nf)
          dr[nf * 16] = f2bf(acc[mf][nf][j] + bv[nf]);
      }
    }
  } else if constexpr (EPI == 1) {
    // scatter + block column sums
    __syncthreads();
    float* smean = (float*)lds;  // [2][128]
    smean[tid] = 0.0f;
    __syncthreads();
    const int b0 = (mblk * 128) / NT;
#pragma unroll
    for (int mf = 0; mf < 4; ++mf) {
      const int baser = mblk * 128 + wm * 64 + mf * 16 + kg * 4;
      const int bb = baser / NT;          // uniform over j (NT % 4 == 0)
      const int bsel = (bb != b0) ? 1 : 0;
      float s[4] = {0.0f, 0.0f, 0.0f, 0.0f};
#pragma unroll
      for (int j = 0; j < 4; ++j) {
        const int row = baser + j;
        const int pix = pixw[row];
        float* dr = aux + ((size_t)bb * HWHW + pix) * 128 + wn * 64 + l16;
#pragma unroll
        for (int nf = 0; nf < 4; ++nf) {
          atomicAdd(dr + nf * 16, acc[mf][nf][j]);
          s[nf] += acc[mf][nf][j];
        }
      }
#pragma unroll
      for (int nf = 0; nf < 4; ++nf)
        atomicAdd(&smean[bsel * 128 + wn * 64 + nf * 16 + l16], s[nf]);
    }
    __syncthreads();
    const int b1 = (mblk * 128 + 127) / NT;
    if (tid < 128) atomicAdd(meanr + (size_t)b0 * 128 + tid, smean[tid]);
    else if (b1 != b0) atomicAdd(meanr + (size_t)b1 * 128 + (tid - 128), smean[tid]);
  } else {
    // EPI 2: logits. head = wn*2 + (nf>>1); reduce over l16 group.
    __syncthreads();
    float* part = (float*)lds;  // [128][4]
    float bv[4];
#pragma unroll
    for (int nf = 0; nf < 4; ++nf)
      bv[nf] = bias[wn * 64 + nf * 16 + l16];
#pragma unroll
    for (int mf = 0; mf < 4; ++mf) {
#pragma unroll
      for (int j = 0; j < 4; ++j) {
        const int rl = wm * 64 + mf * 16 + kg * 4 + j;
        const int row = mblk * 128 + rl;
        const unsigned short* kr = kvb + (size_t)row * 256 + wn * 64 + l16;
        float s0 = (acc[mf][0][j] + bv[0]) * b2f(kr[0]) +
                   (acc[mf][1][j] + bv[1]) * b2f(kr[16]);
        float s1 = (acc[mf][2][j] + bv[2]) * b2f(kr[32]) +
                   (acc[mf][3][j] + bv[3]) * b2f(kr[48]);
        s0 += __shfl_xor(s0, 8, 16); s0 += __shfl_xor(s0, 4, 16);
        s0 += __shfl_xor(s0, 2, 16); s0 += __shfl_xor(s0, 1, 16);
        s1 += __shfl_xor(s1, 8, 16); s1 += __shfl_xor(s1, 4, 16);
        s1 += __shfl_xor(s1, 2, 16); s1 += __shfl_xor(s1, 1, 16);
        if (l16 == 0) {
          part[rl * 4 + wn * 2 + 0] = s0;
          part[rl * 4 + wn * 2 + 1] = s1;
        }
      }
    }
    __syncthreads();
    if (tid < 128) {
      const int row = mblk * 128 + tid;
      const int bb = row / NT, n = row - bb * NT;
#pragma unroll
      for (int h = 0; h < 4; ++h)
        aux[((size_t)bb * NHEADS + h) * NT + n] = part[tid * 4 + h] * SCALE_C;
    }
  }
}

// ---------------------------------------------------------------------------
// k_smpart: per-(bh, chunk) partial max & sum-exp.  NT = 8 * 2500.
// ---------------------------------------------------------------------------
__global__ __launch_bounds__(256) void k_smpart(
    const float* __restrict__ logits, float* __restrict__ pm,
    float* __restrict__ ps)
{
  const int ch = blockIdx.x, bh = blockIdx.y;
  const float* L = logits + (size_t)bh * NT + ch * 2500;
  const int tid = threadIdx.x;
  __shared__ float sred[4];

  float m = -INFINITY;
  for (int i = tid; i < 2500; i += 256) m = fmaxf(m, L[i]);
  m = warpMax(m);
  if ((tid & 63) == 0) sred[tid >> 6] = m;
  __syncthreads();
  m = fmaxf(fmaxf(sred[0], sred[1]), fmaxf(sred[2], sred[3]));

  float s = 0.0f;
  for (int i = tid; i < 2500; i += 256) s += __expf(L[i] - m);
  s = warpSum(s);
  __syncthreads();
  if ((tid & 63) == 0) sred[tid >> 6] = s;
  __syncthreads();
  if (tid == 0) {
    pm[bh * 8 + ch] = m;
    ps[bh * 8 + ch] = sred[0] + sred[1] + sred[2] + sred[3];
  }
}

// ---------------------------------------------------------------------------
// k_cntfix: block b: cnt[b] = #hit pixels. Block 0 also combines softmax
// partials -> smM, smSinv.
// ---------------------------------------------------------------------------
__global__ __launch_bounds__(256) void k_cntfix(
    const float* __restrict__ hits, float* __restrict__ cnt,
    const float* __restrict__ pm, const float* __restrict__ ps,
    float* __restrict__ smM, float* __restrict__ smSinv)
{
  const int b = blockIdx.x;
  const int tid = threadIdx.x;
  float s = 0.0f;
  for (int i = tid; i < HWHW; i += 256)
    s += (hits[(size_t)b * HWHW + i] > 0.0f) ? 1.0f : 0.0f;
  s = warpSum(s);
  __shared__ float sred[4];
  if ((tid & 63) == 0) sred[tid >> 6] = s;
  __syncthreads();
  if (tid == 0) cnt[b] = sred[0] + sred[1] + sred[2] + sred[3];
  if (b == 0 && tid < BB * NHEADS) {
    float M = -INFINITY;
#pragma unroll
    for (int c = 0; c < 8; ++c) M = fmaxf(M, pm[tid * 8 + c]);
    float S = 0.0f;
#pragma unroll
    for (int c = 0; c < 8; ++c) S += ps[tid * 8 + c] * __expf(pm[tid * 8 + c] - M);
    smM[tid] = M;
    smSinv[tid] = 1.0f / S;
  }
}

// ---------------------------------------------------------------------------
// k_final: out[b][c][hw] = lidar + (delta[b][hw][c] - mean*mask)*alpha*gamma
// 80px x 128ch tiles, 512 threads (8 waves, LDS 43.5KB -> 3 blocks/CU = 24
// waves/CU). 80px = 320B = exactly 5 cache lines -> all global I/O 64B-aligned
// full lines. Hits-gated delta reads; XOR-swizzled LDS (<=2-way, free).
// Phase 2: 4 threads per channel row; quad of lanes covers one 64B line.
// ---------------------------------------------------------------------------
__global__ __launch_bounds__(512) void k_final(
    const float* __restrict__ lidar, const float* __restrict__ alpha,
    const float* __restrict__ hits, const float* __restrict__ mean_raw,
    const float* __restrict__ cnt, const float* __restrict__ delta,
    float* __restrict__ out)
{
  __shared__ float tile[80 * 136];
  const int b = blockIdx.y;
  const int p0 = blockIdx.x * 80;
  const int t = threadIdx.x;
  const float4* dsrc = (const float4*)(delta + ((size_t)b * HWHW + p0) * 128);
  const float* hrow = hits + (size_t)b * HWHW + p0;
#pragma unroll
  for (int i = 0; i < 5; ++i) {
    const int idx4 = i * 512 + t;         // 2560 float4 = 80px * 32
    const int p = idx4 >> 5, c4 = idx4 & 31;
    float4 f = make_float4(0.0f, 0.0f, 0.0f, 0.0f);
    if (hrow[p] > 0.0f) f = dsrc[idx4];
    *(float4*)&tile[p * 136 + ((c4 ^ (p & 7)) << 2)] = f;
  }
  __syncthreads();
  const int c = t >> 2, sub = t & 3;
  const int cq = c >> 2, cr = c & 3;
  const float mn = mean_raw[b * 128 + c] / (cnt[b] + EPS_C);
  const size_t cbase = ((size_t)b * CC + c) * HWHW + p0;
  const size_t hbase = (size_t)b * HWHW + p0;
#pragma unroll
  for (int j = 0; j < 5; ++j) {
    const int pq = j * 16 + sub * 4;
    float4 d;
    d.x = tile[(pq + 0) * 136 + (((cq ^ ((pq + 0) & 7)) << 2) | cr)];
    d.y = tile[(pq + 1) * 136 + (((cq ^ ((pq + 1) & 7)) << 2) | cr)];
    d.z = tile[(pq + 2) * 136 + (((cq ^ ((pq + 2) & 7)) << 2) | cr)];
    d.w = tile[(pq + 3) * 136 + (((cq ^ ((pq + 3) & 7)) << 2) | cr)];
    const float4 li = *(const float4*)(lidar + cbase + pq);
    const float4 al = *(const float4*)(alpha + p0 + pq);
    const float4 ht = *(const float4*)(hits + hbase + pq);
    float4 o;
    o.x = li.x + (d.x - (ht.x > 0.0f ? mn : 0.0f)) * al.x * GAMMA_C;
    o.y = li.y + (d.y - (ht.y > 0.0f ? mn : 0.0f)) * al.y * GAMMA_C;
    o.z = li.z + (d.z - (ht.z > 0.0f ? mn : 0.0f)) * al.z * GAMMA_C;
    o.w = li.w + (d.w - (ht.w > 0.0f ? mn : 0.0f)) * al.w * GAMMA_C;
    *(float4*)(out + cbase + pq) = o;
  }
}

// ---------------------------------------------------------------------------
extern "C" void kernel_launch(void* const* d_in, const int* in_sizes, int n_in,
                              void* d_out, int out_size, void* d_ws, size_t ws_size,
                              hipStream_t stream)
{
  const float* lidar  = (const float*)d_in[0];
  const float* tokens = (const float*)d_in[1];
  const float* gate   = (const float*)d_in[2];
  const float* alpha  = (const float*)d_in[3];
  const float* q_w    = (const float*)d_in[4];
  const float* q_b    = (const float*)d_in[5];
  const float* k_w    = (const float*)d_in[6];
  const float* v_w    = (const float*)d_in[7];
  const float* out_w  = (const float*)d_in[8];
  const int*   cidx   = (const int*)d_in[9];
  float* out = (float*)d_out;

  char* W = (char*)d_ws;
  // kv_bf [80000][256] bf16
  unsigned short* kv_bf = (unsigned short*)(W + 0);                 // 40,960,000
  // delta [B][HW][128] f32 (66,355,200). Until its memset this region also
  // hosts lidar_t (at +20,480,000 within; 33,177,600) — dead before memset.
  float* delta = (float*)(W + 61440000);
  unsigned short* lidar_t = (unsigned short*)(W + 81920000);
  float* logits   = (float*)(W + 127795200);   // 1,280,000
  int*   pix_ws   = (int*)(W + 129075200);     //   320,000
  float* hits     = (float*)(W + 129395200);   //   518,400
  float* mean_raw = (float*)(W + 129913600);   //     2,048
  float* cnt      = (float*)(W + 129915648);   //        64
  unsigned short* kvw_bf = (unsigned short*)(W + 129915712);  // 131,072
  unsigned short* qw_bf  = (unsigned short*)(W + 130046784);  //  32,768
  unsigned short* ow_bf  = (unsigned short*)(W + 130079552);  //  32,768
  float* pm     = (float*)(W + 130112320);     // 512
  float* ps     = (float*)(W + 130112832);     // 512
  float* smM    = (float*)(W + 130113344);     // 64
  float* smSinv = (float*)(W + 130113408);     // 64

  hipMemsetAsync(hits, 0, (size_t)BB * HWHW * sizeof(float), stream);
  hipMemsetAsync(mean_raw, 0, 2048 + 64, stream);

  k_prep_pix<<<dim3(409), 256, 0, stream>>>(k_w, v_w, q_w, out_w, kvw_bf,
                                            qw_bf, ow_bf, cidx, pix_ws, hits);
  k_tr2<<<dim3(127, BB, 2), 256, 0, stream>>>(lidar, lidar_t);
  // kv projection: [80000,256] x [256,256]^T
  k_gemm<4, 256, 0, 0, 256><<<dim3(625, 2), 256, 0, stream>>>(
      tokens, nullptr, kvw_bf, nullptr, kv_bf, nullptr, nullptr, nullptr,
      nullptr, nullptr, nullptr, nullptr, nullptr);
  // q projection (rows gathered from lidar_t) -> per-head logits directly
  k_gemm<2, 128, 2, 2, 128><<<dim3(625, 1), 256, 0, stream>>>(
      nullptr, lidar_t, qw_bf, q_b, nullptr, pix_ws, logits, kv_bf,
      nullptr, nullptr, nullptr, nullptr, nullptr);
  // lidar_t dead from here
  hipMemsetAsync(delta, 0, (size_t)BB * HWHW * 128 * sizeof(float), stream);
  k_smpart<<<dim3(8, BB * NHEADS), 256, 0, stream>>>(logits, pm, ps);
  k_cntfix<<<dim3(BB), 256, 0, stream>>>(hits, cnt, pm, ps, smM, smSinv);
  // out projection with fused attention-weighted V + scatter + mean accum
  k_gemm<2, 128, 3, 1, 128><<<dim3(625, 1), 256, 0, stream>>>(
      nullptr, nullptr, ow_bf, nullptr, nullptr, pix_ws, delta, kv_bf,
      mean_raw, smM, smSinv, gate, logits);
  k_final<<<dim3(405, BB), 512, 0, stream>>>(lidar, alpha, hits, mean_raw, cnt,
                                             delta, out);
}